// Round 1
// baseline (1478.122 us; speedup 1.0000x reference)
//
#include <hip/hip_runtime.h>
#include <cstdint>

#define BATCH 4
#define NPTS  8192
#define KNN   5

// ---------------------------------------------------------------------------
// Kernel A: exact 5-NN (largest pdist = -||xi-xj||^2, includes self).
// fp32 fast filter, fp64-exact insert path (exact squares of fp32 diffs).
// Block = 256 queries of one batch; stages points in two 48KB LDS halves.
// ---------------------------------------------------------------------------
__global__ __launch_bounds__(256) void knn_kernel(const float* __restrict__ x,
                                                  int* __restrict__ idx_out) {
    __shared__ float px[4096], py[4096], pz[4096];
    const int b = blockIdx.x >> 5;          // 32 query-chunks per batch
    const int qchunk = blockIdx.x & 31;
    const int q = qchunk * 256 + threadIdx.x;
    const float* xb = x + (size_t)b * 3 * NPTS;

    const float qx = xb[q];
    const float qy = xb[NPTS + q];
    const float qz = xb[2 * NPTS + q];

    double d0 = -1e300, d1 = -1e300, d2 = -1e300, d3 = -1e300, d4 = -1e300;
    int i0 = 0, i1 = 0, i2 = 0, i3 = 0, i4 = 0;
    float thr = -3.0e38f;   // accept-all until 5 slots filled

    for (int half = 0; half < 2; ++half) {
        const int base = half * 4096;
        __syncthreads();
        for (int i = threadIdx.x; i < 4096; i += 256) {
            px[i] = xb[base + i];
            py[i] = xb[NPTS + base + i];
            pz[i] = xb[2 * NPTS + base + i];
        }
        __syncthreads();
        #pragma unroll 4
        for (int m = 0; m < 4096; ++m) {
            const float fx = px[m], fy = py[m], fz = pz[m];
            const float dx = qx - fx, dy = qy - fy, dz = qz - fz;
            const float d32 = -fmaf(dz, dz, fmaf(dy, dy, dx * dx));
            if (d32 > thr) {
                // exact: fp32 diffs are what we have; square/sum in fp64 (exact)
                const double ddx = (double)qx - (double)fx;
                const double ddy = (double)qy - (double)fy;
                const double ddz = (double)qz - (double)fz;
                const double dd = -(ddx * ddx + ddy * ddy + ddz * ddz);
                const int mm = base + m;
                if (dd > d4) {
                    if (dd > d3) {
                        d4 = d3; i4 = i3;
                        if (dd > d2) {
                            d3 = d2; i3 = i2;
                            if (dd > d1) {
                                d2 = d1; i2 = i1;
                                if (dd > d0) { d1 = d0; i1 = i0; d0 = dd; i0 = mm; }
                                else         { d1 = dd; i1 = mm; }
                            } else { d2 = dd; i2 = mm; }
                        } else { d3 = dd; i3 = mm; }
                    } else { d4 = dd; i4 = mm; }
                    thr = (float)d4 - 1e-3f;
                }
            }
        }
    }
    int* o = idx_out + ((size_t)b * NPTS + q) * KNN;
    o[0] = i0; o[1] = i1; o[2] = i2; o[3] = i3; o[4] = i4;
}

// ---------------------------------------------------------------------------
// Kernel B1: gather graph feature + L1 (6->64) + x1max + L2 (64->64) + x2max.
// 16 points/block (80 rows). W1,W2 + activations in LDS (stride 68: 2-way only).
// Writes relu'd h2 to global (scratch in d_out), x1/x2 into cat.
// ---------------------------------------------------------------------------
__global__ __launch_bounds__(256) void mlp12_kernel(const float* __restrict__ x,
                                                    const int* __restrict__ idx,
                                                    const float* __restrict__ w1,
                                                    const float* __restrict__ w2,
                                                    float* __restrict__ h2out,
                                                    float* __restrict__ cat) {
    __shared__ float w1s[64 * 6];
    __shared__ float w2s[64 * 68];
    __shared__ float fbuf[80][6];
    __shared__ float h1s[80 * 68];
    __shared__ float h2s[80 * 68];
    const int t = threadIdx.x;
    const int pbase = blockIdx.x * 16;   // global point id base (b*N+n space)

    for (int i = t; i < 384; i += 256) w1s[i] = w1[i];
    for (int i = t; i < 4096; i += 256) {
        int c = i >> 6, q = i & 63;
        w2s[c * 68 + q] = w2[i];
    }
    if (t < 80) {
        const int pt = pbase + t / 5;
        const int b = pt >> 13;
        const int n = pt & 8191;
        const int k = t % 5;
        const int j = idx[(size_t)pt * KNN + k];
        const float* xb = x + (size_t)b * 3 * NPTS;
        fbuf[t][0] = xb[j];
        fbuf[t][1] = xb[NPTS + j];
        fbuf[t][2] = xb[2 * NPTS + j];
        fbuf[t][3] = xb[n];
        fbuf[t][4] = xb[NPTS + n];
        fbuf[t][5] = xb[2 * NPTS + n];
    }
    __syncthreads();

    // L1: 80 rows x 64 couts, 6 MACs each
    for (int o = t; o < 5120; o += 256) {
        const int r = o >> 6, c = o & 63;
        float acc = 0.f;
        #pragma unroll
        for (int q = 0; q < 6; ++q) acc = fmaf(w1s[c * 6 + q], fbuf[r][q], acc);
        h1s[r * 68 + c] = fmaxf(acc, 0.f);
    }
    __syncthreads();

    // x1 max over k
    for (int o = t; o < 1024; o += 256) {
        const int p = o >> 6, c = o & 63;
        float m = h1s[(p * 5) * 68 + c];
        #pragma unroll
        for (int k = 1; k < 5; ++k) m = fmaxf(m, h1s[(p * 5 + k) * 68 + c]);
        cat[(size_t)(pbase + p) * 512 + c] = m;
    }

    // L2: 4x4 register tiles, 20x16 = 320 tiles
    for (int tile = t; tile < 320; tile += 256) {
        const int r0 = (tile % 20) * 4;
        const int c0 = (tile / 20) * 4;
        float acc[4][4] = {};
        for (int q = 0; q < 64; q += 4) {
            float4 a[4], w[4];
            #pragma unroll
            for (int i = 0; i < 4; ++i) a[i] = *(const float4*)&h1s[(r0 + i) * 68 + q];
            #pragma unroll
            for (int j = 0; j < 4; ++j) w[j] = *(const float4*)&w2s[(c0 + j) * 68 + q];
            #pragma unroll
            for (int i = 0; i < 4; ++i)
                #pragma unroll
                for (int j = 0; j < 4; ++j) {
                    acc[i][j] = fmaf(a[i].x, w[j].x, acc[i][j]);
                    acc[i][j] = fmaf(a[i].y, w[j].y, acc[i][j]);
                    acc[i][j] = fmaf(a[i].z, w[j].z, acc[i][j]);
                    acc[i][j] = fmaf(a[i].w, w[j].w, acc[i][j]);
                }
        }
        #pragma unroll
        for (int i = 0; i < 4; ++i)
            #pragma unroll
            for (int j = 0; j < 4; ++j)
                h2s[(r0 + i) * 68 + c0 + j] = fmaxf(acc[i][j], 0.f);
    }
    __syncthreads();

    // x2 max + h2 global store
    for (int o = t; o < 1024; o += 256) {
        const int p = o >> 6, c = o & 63;
        float m = h2s[(p * 5) * 68 + c];
        #pragma unroll
        for (int k = 1; k < 5; ++k) m = fmaxf(m, h2s[(p * 5 + k) * 68 + c]);
        cat[(size_t)(pbase + p) * 512 + 64 + c] = m;
    }
    for (int o = t; o < 5120; o += 256) {
        const int r = o >> 6, c = o & 63;
        h2out[(size_t)pbase * 320 + o] = h2s[r * 68 + c];
    }
}

// ---------------------------------------------------------------------------
// Kernel B2: L3 (64->128) + x3max. W3 rows live in REGISTERS (2 couts/thread,
// 32 float4 = 128 VGPR); h2 tile (4 points) in LDS, read wave-uniform
// (broadcast, conflict-free). Writes relu'd h3 to ws, x3 into cat.
// ---------------------------------------------------------------------------
__global__ __launch_bounds__(256) void mlp3_kernel(const float* __restrict__ h2g,
                                                   const float* __restrict__ w3,
                                                   float* __restrict__ h3g,
                                                   float* __restrict__ cat) {
    __shared__ float h2t[4 * 5 * 64];
    const int t = threadIdx.x;
    const int p = t >> 6;            // point within group (wave-uniform)
    const int c0 = (t & 63) * 2;     // two output channels

    float4 wreg[2][16];
    #pragma unroll
    for (int j = 0; j < 2; ++j)
        #pragma unroll
        for (int q4 = 0; q4 < 16; ++q4)
            wreg[j][q4] = *(const float4*)&w3[(size_t)(c0 + j) * 64 + q4 * 4];

    for (int g = blockIdx.x; g < BATCH * NPTS / 4; g += gridDim.x) {
        const size_t base = (size_t)g * 4 * 5 * 64;
        __syncthreads();
        for (int i = t; i < 320; i += 256)
            ((float4*)h2t)[i] = ((const float4*)(h2g + base))[i];
        __syncthreads();

        float acc[2][5] = {};
        const float* hp = h2t + p * 320;
        #pragma unroll
        for (int q4 = 0; q4 < 16; ++q4) {
            float4 hk[5];
            #pragma unroll
            for (int k = 0; k < 5; ++k) hk[k] = *(const float4*)&hp[k * 64 + q4 * 4];
            #pragma unroll
            for (int j = 0; j < 2; ++j)
                #pragma unroll
                for (int k = 0; k < 5; ++k) {
                    acc[j][k] = fmaf(wreg[j][q4].x, hk[k].x, acc[j][k]);
                    acc[j][k] = fmaf(wreg[j][q4].y, hk[k].y, acc[j][k]);
                    acc[j][k] = fmaf(wreg[j][q4].z, hk[k].z, acc[j][k]);
                    acc[j][k] = fmaf(wreg[j][q4].w, hk[k].w, acc[j][k]);
                }
        }
        const int pt = g * 4 + p;
        float m0 = 0.f, m1 = 0.f;  // relu'd values are >= 0
        #pragma unroll
        for (int k = 0; k < 5; ++k) {
            const float v0 = fmaxf(acc[0][k], 0.f);
            const float v1 = fmaxf(acc[1][k], 0.f);
            float2 v = make_float2(v0, v1);
            *(float2*)&h3g[((size_t)pt * 5 + k) * 128 + c0] = v;
            m0 = fmaxf(m0, v0);
            m1 = fmaxf(m1, v1);
        }
        *(float2*)&cat[(size_t)pt * 512 + 128 + c0] = make_float2(m0, m1);
    }
}

// ---------------------------------------------------------------------------
// Kernel C: L4 (128->256) + x4max. W4 row in REGISTERS (1 cout/thread,
// 32 float4 = 128 VGPR); blockIdx.y picks the cout quarter. h3 tile (4 points)
// in LDS, broadcast reads. Writes x4 into cat.
// ---------------------------------------------------------------------------
__global__ __launch_bounds__(256) void mlp4_kernel(const float* __restrict__ h3g,
                                                   const float* __restrict__ w4,
                                                   float* __restrict__ cat) {
    __shared__ float h3t[4 * 5 * 128];
    const int t = threadIdx.x;
    const int p = t >> 6;
    const int c = blockIdx.y * 64 + (t & 63);

    float4 wreg[32];
    #pragma unroll
    for (int q4 = 0; q4 < 32; ++q4)
        wreg[q4] = *(const float4*)&w4[(size_t)c * 128 + q4 * 4];

    for (int g = blockIdx.x; g < BATCH * NPTS / 4; g += gridDim.x) {
        const size_t base = (size_t)g * 4 * 5 * 128;
        __syncthreads();
        for (int i = t; i < 640; i += 256)
            ((float4*)h3t)[i] = ((const float4*)(h3g + base))[i];
        __syncthreads();

        float acc[5] = {};
        const float* hp = h3t + p * 640;
        #pragma unroll
        for (int q4 = 0; q4 < 32; ++q4) {
            #pragma unroll
            for (int k = 0; k < 5; ++k) {
                const float4 h = *(const float4*)&hp[k * 128 + q4 * 4];
                acc[k] = fmaf(wreg[q4].x, h.x, acc[k]);
                acc[k] = fmaf(wreg[q4].y, h.y, acc[k]);
                acc[k] = fmaf(wreg[q4].z, h.z, acc[k]);
                acc[k] = fmaf(wreg[q4].w, h.w, acc[k]);
            }
        }
        float m = 0.f;
        #pragma unroll
        for (int k = 0; k < 5; ++k) m = fmaxf(m, fmaxf(acc[k], 0.f));
        cat[(size_t)(g * 4 + p) * 512 + 256 + c] = m;
    }
}

// ---------------------------------------------------------------------------
// Kernel D: final GEMM out(32768,512) = relu( cat(32768,512) * W5^T ), fp32.
// 64x64 tiles, BK=16, 4x4 microtiles. Rows indexed by tx so the epilogue can
// store float4 along n (coalesced 256B runs per column).
// ---------------------------------------------------------------------------
__global__ __launch_bounds__(256) void gemm512_kernel(const float* __restrict__ cat,
                                                      const float* __restrict__ w5,
                                                      float* __restrict__ out) {
    __shared__ float a_s[16][68];
    __shared__ float w_s[16][68];
    const int t = threadIdx.x;
    const int row0 = blockIdx.x * 64;
    const int col0 = blockIdx.y * 64;
    const int tx = t & 15;   // row micro-tile
    const int ty = t >> 4;   // col micro-tile
    const int lr = t >> 2;         // load row 0..63
    const int lk = (t & 3) * 4;    // load k offset

    float acc[4][4] = {};
    for (int kc = 0; kc < 512; kc += 16) {
        const float4 av = *(const float4*)&cat[(size_t)(row0 + lr) * 512 + kc + lk];
        const float4 wv = *(const float4*)&w5[(size_t)(col0 + lr) * 512 + kc + lk];
        __syncthreads();
        a_s[lk + 0][lr] = av.x; a_s[lk + 1][lr] = av.y;
        a_s[lk + 2][lr] = av.z; a_s[lk + 3][lr] = av.w;
        w_s[lk + 0][lr] = wv.x; w_s[lk + 1][lr] = wv.y;
        w_s[lk + 2][lr] = wv.z; w_s[lk + 3][lr] = wv.w;
        __syncthreads();
        #pragma unroll
        for (int kk = 0; kk < 16; ++kk) {
            const float4 a = *(const float4*)&a_s[kk][tx * 4];
            const float4 w = *(const float4*)&w_s[kk][ty * 4];
            acc[0][0] = fmaf(a.x, w.x, acc[0][0]); acc[0][1] = fmaf(a.x, w.y, acc[0][1]);
            acc[0][2] = fmaf(a.x, w.z, acc[0][2]); acc[0][3] = fmaf(a.x, w.w, acc[0][3]);
            acc[1][0] = fmaf(a.y, w.x, acc[1][0]); acc[1][1] = fmaf(a.y, w.y, acc[1][1]);
            acc[1][2] = fmaf(a.y, w.z, acc[1][2]); acc[1][3] = fmaf(a.y, w.w, acc[1][3]);
            acc[2][0] = fmaf(a.z, w.x, acc[2][0]); acc[2][1] = fmaf(a.z, w.y, acc[2][1]);
            acc[2][2] = fmaf(a.z, w.z, acc[2][2]); acc[2][3] = fmaf(a.z, w.w, acc[2][3]);
            acc[3][0] = fmaf(a.w, w.x, acc[3][0]); acc[3][1] = fmaf(a.w, w.y, acc[3][1]);
            acc[3][2] = fmaf(a.w, w.z, acc[3][2]); acc[3][3] = fmaf(a.w, w.w, acc[3][3]);
        }
    }

    // epilogue: out layout (B, 512, N); rows are n-contiguous via tx
    const int rbase = row0 + tx * 4;
    const int b = rbase >> 13;
    const int nbase = rbase & 8191;
    #pragma unroll
    for (int j = 0; j < 4; ++j) {
        const int col = col0 + ty * 4 + j;
        float4 v = make_float4(fmaxf(acc[0][j], 0.f), fmaxf(acc[1][j], 0.f),
                               fmaxf(acc[2][j], 0.f), fmaxf(acc[3][j], 0.f));
        *(float4*)&out[((size_t)b * 512 + col) * NPTS + nbase] = v;
    }
}

extern "C" void kernel_launch(void* const* d_in, const int* in_sizes, int n_in,
                              void* d_out, int out_size, void* d_ws, size_t ws_size,
                              hipStream_t stream) {
    (void)in_sizes; (void)n_in; (void)out_size; (void)ws_size;
    const float* x  = (const float*)d_in[0];
    const float* w1 = (const float*)d_in[1];
    const float* w2 = (const float*)d_in[2];
    const float* w3 = (const float*)d_in[3];
    const float* w4 = (const float*)d_in[4];
    const float* w5 = (const float*)d_in[5];
    float* out = (float*)d_out;

    // workspace layout
    char* ws = (char*)d_ws;
    int*   idx = (int*)ws;                                   // 4*8192*5*4   = 0.66 MB
    float* cat = (float*)(ws + (1u << 20));                  // 4*8192*512*4 = 64 MB
    float* h3  = (float*)(ws + (1u << 20) + (64u << 20));    // 4*8192*5*128*4 = 80 MB
    float* h2  = out;                                        // scratch: 40 MB <= 64 MB out

    knn_kernel<<<dim3(BATCH * 32), dim3(256), 0, stream>>>(x, idx);
    mlp12_kernel<<<dim3(BATCH * NPTS / 16), dim3(256), 0, stream>>>(x, idx, w1, w2, h2, cat);
    mlp3_kernel<<<dim3(256), dim3(256), 0, stream>>>(h2, w3, h3, cat);
    mlp4_kernel<<<dim3(256, 4), dim3(256), 0, stream>>>(h3, w4, cat);
    gemm512_kernel<<<dim3(BATCH * NPTS / 64, 8), dim3(256), 0, stream>>>(cat, w5, out);
}

// Round 2
// 937.418 us; speedup vs baseline: 1.5768x; 1.5768x over previous
//
#include <hip/hip_runtime.h>
#include <cstdint>

#define BATCH 4
#define NPTS  8192
#define KNN   5

// ---------------------------------------------------------------------------
// Kernel A: exact 5-NN (largest pdist = -||xi-xj||^2, includes self).
// v2: 64 queries/block, 4 wave-uniform candidate slices per query -> 512
// blocks (4x parallelism vs v1). fp32 fast filter with 1e-3 margin, fp64-exact
// insert path. Per-slice exact top-5, then 4-way sorted merge with (dist,idx)
// tie-break (lower index wins) matching jax.lax.top_k.
// LDS: 48KB staging, re-aliased for the merge lists.
// ---------------------------------------------------------------------------
__global__ __launch_bounds__(256) void knn_kernel(const float* __restrict__ x,
                                                  int* __restrict__ idx_out) {
    __shared__ alignas(16) float stage[3 * 4096];   // 48 KB
    float* px = stage;
    float* py = stage + 4096;
    float* pz = stage + 8192;

    const int t = threadIdx.x;
    const int q = t & 63;          // query within block
    const int s = t >> 6;          // slice id 0..3 (wave-uniform)
    const int b = blockIdx.x >> 7; // 128 blocks per batch
    const int qg = (blockIdx.x & 127) * 64 + q;
    const float* xb = x + (size_t)b * 3 * NPTS;

    const float qx = xb[qg];
    const float qy = xb[NPTS + qg];
    const float qz = xb[2 * NPTS + qg];

    double d0 = -1e300, d1 = -1e300, d2 = -1e300, d3 = -1e300, d4 = -1e300;
    int i0 = 0, i1 = 0, i2 = 0, i3 = 0, i4 = 0;
    float thr = -3.0e38f;   // accept-all until 5 slots filled

    for (int half = 0; half < 2; ++half) {
        const int base = half * 4096;
        __syncthreads();
        for (int i = t; i < 4096; i += 256) {
            px[i] = xb[base + i];
            py[i] = xb[NPTS + base + i];
            pz[i] = xb[2 * NPTS + base + i];
        }
        __syncthreads();
        const int mlo = s * 1024;
        #pragma unroll 4
        for (int m = mlo; m < mlo + 1024; ++m) {
            const float fx = px[m], fy = py[m], fz = pz[m];
            const float dx = qx - fx, dy = qy - fy, dz = qz - fz;
            const float d32 = -fmaf(dz, dz, fmaf(dy, dy, dx * dx));
            if (d32 > thr) {
                const double ddx = (double)qx - (double)fx;
                const double ddy = (double)qy - (double)fy;
                const double ddz = (double)qz - (double)fz;
                const double dd = -(ddx * ddx + ddy * ddy + ddz * ddz);
                const int mm = base + m;
                if (dd > d4) {
                    if (dd > d3) {
                        d4 = d3; i4 = i3;
                        if (dd > d2) {
                            d3 = d2; i3 = i2;
                            if (dd > d1) {
                                d2 = d1; i2 = i1;
                                if (dd > d0) { d1 = d0; i1 = i0; d0 = dd; i0 = mm; }
                                else         { d1 = dd; i1 = mm; }
                            } else { d2 = dd; i2 = mm; }
                        } else { d3 = dd; i3 = mm; }
                    } else { d4 = dd; i4 = mm; }
                    thr = (float)d4 - 1e-3f;
                }
            }
        }
    }

    // ---- merge: alias the staging buffer ----
    __syncthreads();   // everyone done reading px/py/pz
    double* dm = (double*)stage;          // 4*64*5 doubles = 10240 B
    int*    im = (int*)(stage + 2560);    // 4*64*5 ints    =  5120 B
    const int e = (s * 64 + q) * 5;
    dm[e + 0] = d0; dm[e + 1] = d1; dm[e + 2] = d2; dm[e + 3] = d3; dm[e + 4] = d4;
    im[e + 0] = i0; im[e + 1] = i1; im[e + 2] = i2; im[e + 3] = i3; im[e + 4] = i4;
    __syncthreads();

    if (t < 64) {
        // 4-way merge of sorted-desc lists; tie -> lower index (top_k semantics)
        int    cur[4] = {0, 0, 0, 0};
        double hd[4];
        int    hi[4];
        #pragma unroll
        for (int w = 0; w < 4; ++w) {
            hd[w] = dm[(w * 64 + t) * 5];
            hi[w] = im[(w * 64 + t) * 5];
        }
        int* o = idx_out + ((size_t)b * NPTS + (blockIdx.x & 127) * 64 + t) * KNN;
        #pragma unroll
        for (int r = 0; r < KNN; ++r) {
            int wbest = 0;
            #pragma unroll
            for (int w = 1; w < 4; ++w) {
                const bool better = (hd[w] > hd[wbest]) ||
                                    (hd[w] == hd[wbest] && hi[w] < hi[wbest]);
                if (better) wbest = w;
            }
            o[r] = hi[wbest];
            const int c = ++cur[wbest];
            if (c < KNN) {
                hd[wbest] = dm[(wbest * 64 + t) * 5 + c];
                hi[wbest] = im[(wbest * 64 + t) * 5 + c];
            } else {
                hd[wbest] = -1e301;
                hi[wbest] = 0x7fffffff;
            }
        }
    }
}

// ---------------------------------------------------------------------------
// Kernel B1: gather graph feature + L1 (6->64) + x1max + L2 (64->64) + x2max.
// 16 points/block (80 rows). W1,W2 + activations in LDS (stride 68: 2-way only).
// Writes relu'd h2 to global (scratch in d_out), x1/x2 into cat.
// ---------------------------------------------------------------------------
__global__ __launch_bounds__(256) void mlp12_kernel(const float* __restrict__ x,
                                                    const int* __restrict__ idx,
                                                    const float* __restrict__ w1,
                                                    const float* __restrict__ w2,
                                                    float* __restrict__ h2out,
                                                    float* __restrict__ cat) {
    __shared__ float w1s[64 * 6];
    __shared__ float w2s[64 * 68];
    __shared__ float fbuf[80][6];
    __shared__ float h1s[80 * 68];
    __shared__ float h2s[80 * 68];
    const int t = threadIdx.x;
    const int pbase = blockIdx.x * 16;   // global point id base (b*N+n space)

    for (int i = t; i < 384; i += 256) w1s[i] = w1[i];
    for (int i = t; i < 4096; i += 256) {
        int c = i >> 6, q = i & 63;
        w2s[c * 68 + q] = w2[i];
    }
    if (t < 80) {
        const int pt = pbase + t / 5;
        const int b = pt >> 13;
        const int n = pt & 8191;
        const int k = t % 5;
        const int j = idx[(size_t)pt * KNN + k];
        const float* xb = x + (size_t)b * 3 * NPTS;
        fbuf[t][0] = xb[j];
        fbuf[t][1] = xb[NPTS + j];
        fbuf[t][2] = xb[2 * NPTS + j];
        fbuf[t][3] = xb[n];
        fbuf[t][4] = xb[NPTS + n];
        fbuf[t][5] = xb[2 * NPTS + n];
    }
    __syncthreads();

    // L1: 80 rows x 64 couts, 6 MACs each
    for (int o = t; o < 5120; o += 256) {
        const int r = o >> 6, c = o & 63;
        float acc = 0.f;
        #pragma unroll
        for (int q = 0; q < 6; ++q) acc = fmaf(w1s[c * 6 + q], fbuf[r][q], acc);
        h1s[r * 68 + c] = fmaxf(acc, 0.f);
    }
    __syncthreads();

    // x1 max over k
    for (int o = t; o < 1024; o += 256) {
        const int p = o >> 6, c = o & 63;
        float m = h1s[(p * 5) * 68 + c];
        #pragma unroll
        for (int k = 1; k < 5; ++k) m = fmaxf(m, h1s[(p * 5 + k) * 68 + c]);
        cat[(size_t)(pbase + p) * 512 + c] = m;
    }

    // L2: 4x4 register tiles, 20x16 = 320 tiles
    for (int tile = t; tile < 320; tile += 256) {
        const int r0 = (tile % 20) * 4;
        const int c0 = (tile / 20) * 4;
        float acc[4][4] = {};
        for (int q = 0; q < 64; q += 4) {
            float4 a[4], w[4];
            #pragma unroll
            for (int i = 0; i < 4; ++i) a[i] = *(const float4*)&h1s[(r0 + i) * 68 + q];
            #pragma unroll
            for (int j = 0; j < 4; ++j) w[j] = *(const float4*)&w2s[(c0 + j) * 68 + q];
            #pragma unroll
            for (int i = 0; i < 4; ++i)
                #pragma unroll
                for (int j = 0; j < 4; ++j) {
                    acc[i][j] = fmaf(a[i].x, w[j].x, acc[i][j]);
                    acc[i][j] = fmaf(a[i].y, w[j].y, acc[i][j]);
                    acc[i][j] = fmaf(a[i].z, w[j].z, acc[i][j]);
                    acc[i][j] = fmaf(a[i].w, w[j].w, acc[i][j]);
                }
        }
        #pragma unroll
        for (int i = 0; i < 4; ++i)
            #pragma unroll
            for (int j = 0; j < 4; ++j)
                h2s[(r0 + i) * 68 + c0 + j] = fmaxf(acc[i][j], 0.f);
    }
    __syncthreads();

    // x2 max + h2 global store
    for (int o = t; o < 1024; o += 256) {
        const int p = o >> 6, c = o & 63;
        float m = h2s[(p * 5) * 68 + c];
        #pragma unroll
        for (int k = 1; k < 5; ++k) m = fmaxf(m, h2s[(p * 5 + k) * 68 + c]);
        cat[(size_t)(pbase + p) * 512 + 64 + c] = m;
    }
    for (int o = t; o < 5120; o += 256) {
        const int r = o >> 6, c = o & 63;
        h2out[(size_t)pbase * 320 + o] = h2s[r * 68 + c];
    }
}

// ---------------------------------------------------------------------------
// Kernel B2: L3 (64->128) + x3max. W3 rows live in REGISTERS (2 couts/thread,
// 32 float4 = 128 VGPR); h2 tile (4 points) in LDS, read wave-uniform
// (broadcast, conflict-free). Writes relu'd h3 to ws, x3 into cat.
// ---------------------------------------------------------------------------
__global__ __launch_bounds__(256) void mlp3_kernel(const float* __restrict__ h2g,
                                                   const float* __restrict__ w3,
                                                   float* __restrict__ h3g,
                                                   float* __restrict__ cat) {
    __shared__ float h2t[4 * 5 * 64];
    const int t = threadIdx.x;
    const int p = t >> 6;            // point within group (wave-uniform)
    const int c0 = (t & 63) * 2;     // two output channels

    float4 wreg[2][16];
    #pragma unroll
    for (int j = 0; j < 2; ++j)
        #pragma unroll
        for (int q4 = 0; q4 < 16; ++q4)
            wreg[j][q4] = *(const float4*)&w3[(size_t)(c0 + j) * 64 + q4 * 4];

    for (int g = blockIdx.x; g < BATCH * NPTS / 4; g += gridDim.x) {
        const size_t base = (size_t)g * 4 * 5 * 64;
        __syncthreads();
        for (int i = t; i < 320; i += 256)
            ((float4*)h2t)[i] = ((const float4*)(h2g + base))[i];
        __syncthreads();

        float acc[2][5] = {};
        const float* hp = h2t + p * 320;
        #pragma unroll
        for (int q4 = 0; q4 < 16; ++q4) {
            float4 hk[5];
            #pragma unroll
            for (int k = 0; k < 5; ++k) hk[k] = *(const float4*)&hp[k * 64 + q4 * 4];
            #pragma unroll
            for (int j = 0; j < 2; ++j)
                #pragma unroll
                for (int k = 0; k < 5; ++k) {
                    acc[j][k] = fmaf(wreg[j][q4].x, hk[k].x, acc[j][k]);
                    acc[j][k] = fmaf(wreg[j][q4].y, hk[k].y, acc[j][k]);
                    acc[j][k] = fmaf(wreg[j][q4].z, hk[k].z, acc[j][k]);
                    acc[j][k] = fmaf(wreg[j][q4].w, hk[k].w, acc[j][k]);
                }
        }
        const int pt = g * 4 + p;
        float m0 = 0.f, m1 = 0.f;  // relu'd values are >= 0
        #pragma unroll
        for (int k = 0; k < 5; ++k) {
            const float v0 = fmaxf(acc[0][k], 0.f);
            const float v1 = fmaxf(acc[1][k], 0.f);
            float2 v = make_float2(v0, v1);
            *(float2*)&h3g[((size_t)pt * 5 + k) * 128 + c0] = v;
            m0 = fmaxf(m0, v0);
            m1 = fmaxf(m1, v1);
        }
        *(float2*)&cat[(size_t)pt * 512 + 128 + c0] = make_float2(m0, m1);
    }
}

// ---------------------------------------------------------------------------
// Kernel C: L4 (128->256) + x4max. W4 row in REGISTERS (1 cout/thread,
// 32 float4 = 128 VGPR); blockIdx.y picks the cout quarter. h3 tile (4 points)
// in LDS, broadcast reads. Writes x4 into cat.
// ---------------------------------------------------------------------------
__global__ __launch_bounds__(256) void mlp4_kernel(const float* __restrict__ h3g,
                                                   const float* __restrict__ w4,
                                                   float* __restrict__ cat) {
    __shared__ float h3t[4 * 5 * 128];
    const int t = threadIdx.x;
    const int p = t >> 6;
    const int c = blockIdx.y * 64 + (t & 63);

    float4 wreg[32];
    #pragma unroll
    for (int q4 = 0; q4 < 32; ++q4)
        wreg[q4] = *(const float4*)&w4[(size_t)c * 128 + q4 * 4];

    for (int g = blockIdx.x; g < BATCH * NPTS / 4; g += gridDim.x) {
        const size_t base = (size_t)g * 4 * 5 * 128;
        __syncthreads();
        for (int i = t; i < 640; i += 256)
            ((float4*)h3t)[i] = ((const float4*)(h3g + base))[i];
        __syncthreads();

        float acc[5] = {};
        const float* hp = h3t + p * 640;
        #pragma unroll
        for (int q4 = 0; q4 < 32; ++q4) {
            #pragma unroll
            for (int k = 0; k < 5; ++k) {
                const float4 h = *(const float4*)&hp[k * 128 + q4 * 4];
                acc[k] = fmaf(wreg[q4].x, h.x, acc[k]);
                acc[k] = fmaf(wreg[q4].y, h.y, acc[k]);
                acc[k] = fmaf(wreg[q4].z, h.z, acc[k]);
                acc[k] = fmaf(wreg[q4].w, h.w, acc[k]);
            }
        }
        float m = 0.f;
        #pragma unroll
        for (int k = 0; k < 5; ++k) m = fmaxf(m, fmaxf(acc[k], 0.f));
        cat[(size_t)(g * 4 + p) * 512 + 256 + c] = m;
    }
}

// ---------------------------------------------------------------------------
// Kernel D: final GEMM out(32768,512) = relu( cat(32768,512) * W5^T ), fp32.
// 64x64 tiles, BK=16, 4x4 microtiles. Rows indexed by tx so the epilogue can
// store float4 along n (coalesced 256B runs per column).
// ---------------------------------------------------------------------------
__global__ __launch_bounds__(256) void gemm512_kernel(const float* __restrict__ cat,
                                                      const float* __restrict__ w5,
                                                      float* __restrict__ out) {
    __shared__ float a_s[16][68];
    __shared__ float w_s[16][68];
    const int t = threadIdx.x;
    const int row0 = blockIdx.x * 64;
    const int col0 = blockIdx.y * 64;
    const int tx = t & 15;   // row micro-tile
    const int ty = t >> 4;   // col micro-tile
    const int lr = t >> 2;         // load row 0..63
    const int lk = (t & 3) * 4;    // load k offset

    float acc[4][4] = {};
    for (int kc = 0; kc < 512; kc += 16) {
        const float4 av = *(const float4*)&cat[(size_t)(row0 + lr) * 512 + kc + lk];
        const float4 wv = *(const float4*)&w5[(size_t)(col0 + lr) * 512 + kc + lk];
        __syncthreads();
        a_s[lk + 0][lr] = av.x; a_s[lk + 1][lr] = av.y;
        a_s[lk + 2][lr] = av.z; a_s[lk + 3][lr] = av.w;
        w_s[lk + 0][lr] = wv.x; w_s[lk + 1][lr] = wv.y;
        w_s[lk + 2][lr] = wv.z; w_s[lk + 3][lr] = wv.w;
        __syncthreads();
        #pragma unroll
        for (int kk = 0; kk < 16; ++kk) {
            const float4 a = *(const float4*)&a_s[kk][tx * 4];
            const float4 w = *(const float4*)&w_s[kk][ty * 4];
            acc[0][0] = fmaf(a.x, w.x, acc[0][0]); acc[0][1] = fmaf(a.x, w.y, acc[0][1]);
            acc[0][2] = fmaf(a.x, w.z, acc[0][2]); acc[0][3] = fmaf(a.x, w.w, acc[0][3]);
            acc[1][0] = fmaf(a.y, w.x, acc[1][0]); acc[1][1] = fmaf(a.y, w.y, acc[1][1]);
            acc[1][2] = fmaf(a.y, w.z, acc[1][2]); acc[1][3] = fmaf(a.y, w.w, acc[1][3]);
            acc[2][0] = fmaf(a.z, w.x, acc[2][0]); acc[2][1] = fmaf(a.z, w.y, acc[2][1]);
            acc[2][2] = fmaf(a.z, w.z, acc[2][2]); acc[2][3] = fmaf(a.z, w.w, acc[2][3]);
            acc[3][0] = fmaf(a.w, w.x, acc[3][0]); acc[3][1] = fmaf(a.w, w.y, acc[3][1]);
            acc[3][2] = fmaf(a.w, w.z, acc[3][2]); acc[3][3] = fmaf(a.w, w.w, acc[3][3]);
        }
    }

    // epilogue: out layout (B, 512, N); rows are n-contiguous via tx
    const int rbase = row0 + tx * 4;
    const int b = rbase >> 13;
    const int nbase = rbase & 8191;
    #pragma unroll
    for (int j = 0; j < 4; ++j) {
        const int col = col0 + ty * 4 + j;
        float4 v = make_float4(fmaxf(acc[0][j], 0.f), fmaxf(acc[1][j], 0.f),
                               fmaxf(acc[2][j], 0.f), fmaxf(acc[3][j], 0.f));
        *(float4*)&out[((size_t)b * 512 + col) * NPTS + nbase] = v;
    }
}

extern "C" void kernel_launch(void* const* d_in, const int* in_sizes, int n_in,
                              void* d_out, int out_size, void* d_ws, size_t ws_size,
                              hipStream_t stream) {
    (void)in_sizes; (void)n_in; (void)out_size; (void)ws_size;
    const float* x  = (const float*)d_in[0];
    const float* w1 = (const float*)d_in[1];
    const float* w2 = (const float*)d_in[2];
    const float* w3 = (const float*)d_in[3];
    const float* w4 = (const float*)d_in[4];
    const float* w5 = (const float*)d_in[5];
    float* out = (float*)d_out;

    // workspace layout
    char* ws = (char*)d_ws;
    int*   idx = (int*)ws;                                   // 4*8192*5*4   = 0.66 MB
    float* cat = (float*)(ws + (1u << 20));                  // 4*8192*512*4 = 64 MB
    float* h3  = (float*)(ws + (1u << 20) + (64u << 20));    // 4*8192*5*128*4 = 80 MB
    float* h2  = out;                                        // scratch: 40 MB <= 64 MB out

    knn_kernel<<<dim3(BATCH * NPTS / 64), dim3(256), 0, stream>>>(x, idx);
    mlp12_kernel<<<dim3(BATCH * NPTS / 16), dim3(256), 0, stream>>>(x, idx, w1, w2, h2, cat);
    mlp3_kernel<<<dim3(256), dim3(256), 0, stream>>>(h2, w3, h3, cat);
    mlp4_kernel<<<dim3(256, 4), dim3(256), 0, stream>>>(h3, w4, cat);
    gemm512_kernel<<<dim3(BATCH * NPTS / 64, 8), dim3(256), 0, stream>>>(cat, w5, out);
}

// Round 3
// 864.749 us; speedup vs baseline: 1.7093x; 1.0840x over previous
//
#include <hip/hip_runtime.h>
#include <cstdint>

#define BATCH 4
#define NPTS  8192
#define KNN   5

// ---------------------------------------------------------------------------
// Kernel A: exact 5-NN (largest pdist = -||xi-xj||^2, includes self).
// v3: 64 queries/block, 8 wave-uniform slices (512 threads). Candidates read
// from LDS as float4 broadcasts (ds_read_b128, conflict-free): 0.75 LDS
// instr/candidate vs 3 in v2. One filter branch per 4-candidate group.
// fp32 fast filter (1e-3 margin), fp64-exact insert path. 8-way sorted merge
// with (dist,idx) tie-break (lower index wins) matching jax.lax.top_k.
// ---------------------------------------------------------------------------
__global__ __launch_bounds__(512) void knn_kernel(const float* __restrict__ x,
                                                  int* __restrict__ idx_out) {
    __shared__ alignas(16) float stage[3 * 4096];   // 48 KB
    float* px = stage;
    float* py = stage + 4096;
    float* pz = stage + 8192;

    const int t = threadIdx.x;
    const int q = t & 63;          // query within block (lane)
    const int w = t >> 6;          // wave/slice id 0..7 (wave-uniform)
    const int b = blockIdx.x >> 7; // 128 blocks per batch
    const int qg = (blockIdx.x & 127) * 64 + q;
    const float* xb = x + (size_t)b * 3 * NPTS;

    const float qx = xb[qg];
    const float qy = xb[NPTS + qg];
    const float qz = xb[2 * NPTS + qg];

    double d0 = -1e300, d1 = -1e300, d2 = -1e300, d3 = -1e300, d4 = -1e300;
    int i0 = 0, i1 = 0, i2 = 0, i3 = 0, i4 = 0;
    float thr = -3.0e38f;   // accept-all until 5 slots filled

    for (int half = 0; half < 2; ++half) {
        const int base = half * 4096;
        __syncthreads();
        {
            const float4* gx = (const float4*)(xb + base);
            const float4* gy = (const float4*)(xb + NPTS + base);
            const float4* gz = (const float4*)(xb + 2 * NPTS + base);
            for (int i = t; i < 1024; i += 512) {
                ((float4*)px)[i] = gx[i];
                ((float4*)py)[i] = gy[i];
                ((float4*)pz)[i] = gz[i];
            }
        }
        __syncthreads();
        const int glo = w * 128;            // 128 float4-groups = 512 candidates
        #pragma unroll 2
        for (int g = glo; g < glo + 128; ++g) {
            const float4 fx4 = ((const float4*)px)[g];
            const float4 fy4 = ((const float4*)py)[g];
            const float4 fz4 = ((const float4*)pz)[g];
            float d32[4];
            {
                const float dx = qx - fx4.x, dy = qy - fy4.x, dz = qz - fz4.x;
                d32[0] = -fmaf(dz, dz, fmaf(dy, dy, dx * dx));
            }
            {
                const float dx = qx - fx4.y, dy = qy - fy4.y, dz = qz - fz4.y;
                d32[1] = -fmaf(dz, dz, fmaf(dy, dy, dx * dx));
            }
            {
                const float dx = qx - fx4.z, dy = qy - fy4.z, dz = qz - fz4.z;
                d32[2] = -fmaf(dz, dz, fmaf(dy, dy, dx * dx));
            }
            {
                const float dx = qx - fx4.w, dy = qy - fy4.w, dz = qz - fz4.w;
                d32[3] = -fmaf(dz, dz, fmaf(dy, dy, dx * dx));
            }
            const float dmax = fmaxf(fmaxf(d32[0], d32[1]), fmaxf(d32[2], d32[3]));
            if (dmax > thr) {
                const float fxs[4] = {fx4.x, fx4.y, fx4.z, fx4.w};
                const float fys[4] = {fy4.x, fy4.y, fy4.z, fy4.w};
                const float fzs[4] = {fz4.x, fz4.y, fz4.z, fz4.w};
                #pragma unroll
                for (int j = 0; j < 4; ++j) {
                    if (d32[j] > thr) {
                        const double ddx = (double)qx - (double)fxs[j];
                        const double ddy = (double)qy - (double)fys[j];
                        const double ddz = (double)qz - (double)fzs[j];
                        const double dd = -(ddx * ddx + ddy * ddy + ddz * ddz);
                        const int mm = base + g * 4 + j;
                        if (dd > d4) {
                            if (dd > d3) {
                                d4 = d3; i4 = i3;
                                if (dd > d2) {
                                    d3 = d2; i3 = i2;
                                    if (dd > d1) {
                                        d2 = d1; i2 = i1;
                                        if (dd > d0) { d1 = d0; i1 = i0; d0 = dd; i0 = mm; }
                                        else         { d1 = dd; i1 = mm; }
                                    } else { d2 = dd; i2 = mm; }
                                } else { d3 = dd; i3 = mm; }
                            } else { d4 = dd; i4 = mm; }
                            thr = (float)d4 - 1e-3f;
                        }
                    }
                }
            }
        }
    }

    // ---- merge: alias the staging buffer ----
    __syncthreads();   // everyone done reading px/py/pz
    double* dm = (double*)stage;          // 8*64*5 doubles = 20480 B
    int*    im = (int*)(stage + 5120);    // 8*64*5 ints    = 10240 B
    const int e = (w * 64 + q) * 5;
    dm[e + 0] = d0; dm[e + 1] = d1; dm[e + 2] = d2; dm[e + 3] = d3; dm[e + 4] = d4;
    im[e + 0] = i0; im[e + 1] = i1; im[e + 2] = i2; im[e + 3] = i3; im[e + 4] = i4;
    __syncthreads();

    if (t < 64) {
        // 8-way merge of sorted-desc lists; tie -> lower index (top_k semantics)
        int    cur[8] = {0, 0, 0, 0, 0, 0, 0, 0};
        double hd[8];
        int    hi[8];
        #pragma unroll
        for (int ww = 0; ww < 8; ++ww) {
            hd[ww] = dm[(ww * 64 + t) * 5];
            hi[ww] = im[(ww * 64 + t) * 5];
        }
        int* o = idx_out + ((size_t)b * NPTS + (blockIdx.x & 127) * 64 + t) * KNN;
        #pragma unroll
        for (int r = 0; r < KNN; ++r) {
            int wbest = 0;
            #pragma unroll
            for (int ww = 1; ww < 8; ++ww) {
                const bool better = (hd[ww] > hd[wbest]) ||
                                    (hd[ww] == hd[wbest] && hi[ww] < hi[wbest]);
                if (better) wbest = ww;
            }
            o[r] = hi[wbest];
            const int c = ++cur[wbest];
            if (c < KNN) {
                hd[wbest] = dm[(wbest * 64 + t) * 5 + c];
                hi[wbest] = im[(wbest * 64 + t) * 5 + c];
            } else {
                hd[wbest] = -1e301;
                hi[wbest] = 0x7fffffff;
            }
        }
    }
}

// ---------------------------------------------------------------------------
// Kernel B1: gather graph feature + L1 (6->64) + x1max + L2 (64->64) + x2max.
// 16 points/block (80 rows). W1,W2 + activations in LDS (stride 68: 2-way only).
// Writes relu'd h2 to global (scratch in d_out), x1/x2 into cat.
// ---------------------------------------------------------------------------
__global__ __launch_bounds__(256) void mlp12_kernel(const float* __restrict__ x,
                                                    const int* __restrict__ idx,
                                                    const float* __restrict__ w1,
                                                    const float* __restrict__ w2,
                                                    float* __restrict__ h2out,
                                                    float* __restrict__ cat) {
    __shared__ float w1s[64 * 6];
    __shared__ float w2s[64 * 68];
    __shared__ float fbuf[80][6];
    __shared__ float h1s[80 * 68];
    __shared__ float h2s[80 * 68];
    const int t = threadIdx.x;
    const int pbase = blockIdx.x * 16;   // global point id base (b*N+n space)

    for (int i = t; i < 384; i += 256) w1s[i] = w1[i];
    for (int i = t; i < 4096; i += 256) {
        int c = i >> 6, q = i & 63;
        w2s[c * 68 + q] = w2[i];
    }
    if (t < 80) {
        const int pt = pbase + t / 5;
        const int b = pt >> 13;
        const int n = pt & 8191;
        const int k = t % 5;
        const int j = idx[(size_t)pt * KNN + k];
        const float* xb = x + (size_t)b * 3 * NPTS;
        fbuf[t][0] = xb[j];
        fbuf[t][1] = xb[NPTS + j];
        fbuf[t][2] = xb[2 * NPTS + j];
        fbuf[t][3] = xb[n];
        fbuf[t][4] = xb[NPTS + n];
        fbuf[t][5] = xb[2 * NPTS + n];
    }
    __syncthreads();

    // L1: 80 rows x 64 couts, 6 MACs each
    for (int o = t; o < 5120; o += 256) {
        const int r = o >> 6, c = o & 63;
        float acc = 0.f;
        #pragma unroll
        for (int q = 0; q < 6; ++q) acc = fmaf(w1s[c * 6 + q], fbuf[r][q], acc);
        h1s[r * 68 + c] = fmaxf(acc, 0.f);
    }
    __syncthreads();

    // x1 max over k
    for (int o = t; o < 1024; o += 256) {
        const int p = o >> 6, c = o & 63;
        float m = h1s[(p * 5) * 68 + c];
        #pragma unroll
        for (int k = 1; k < 5; ++k) m = fmaxf(m, h1s[(p * 5 + k) * 68 + c]);
        cat[(size_t)(pbase + p) * 512 + c] = m;
    }

    // L2: 4x4 register tiles, 20x16 = 320 tiles
    for (int tile = t; tile < 320; tile += 256) {
        const int r0 = (tile % 20) * 4;
        const int c0 = (tile / 20) * 4;
        float acc[4][4] = {};
        for (int q = 0; q < 64; q += 4) {
            float4 a[4], w[4];
            #pragma unroll
            for (int i = 0; i < 4; ++i) a[i] = *(const float4*)&h1s[(r0 + i) * 68 + q];
            #pragma unroll
            for (int j = 0; j < 4; ++j) w[j] = *(const float4*)&w2s[(c0 + j) * 68 + q];
            #pragma unroll
            for (int i = 0; i < 4; ++i)
                #pragma unroll
                for (int j = 0; j < 4; ++j) {
                    acc[i][j] = fmaf(a[i].x, w[j].x, acc[i][j]);
                    acc[i][j] = fmaf(a[i].y, w[j].y, acc[i][j]);
                    acc[i][j] = fmaf(a[i].z, w[j].z, acc[i][j]);
                    acc[i][j] = fmaf(a[i].w, w[j].w, acc[i][j]);
                }
        }
        #pragma unroll
        for (int i = 0; i < 4; ++i)
            #pragma unroll
            for (int j = 0; j < 4; ++j)
                h2s[(r0 + i) * 68 + c0 + j] = fmaxf(acc[i][j], 0.f);
    }
    __syncthreads();

    // x2 max + h2 global store
    for (int o = t; o < 1024; o += 256) {
        const int p = o >> 6, c = o & 63;
        float m = h2s[(p * 5) * 68 + c];
        #pragma unroll
        for (int k = 1; k < 5; ++k) m = fmaxf(m, h2s[(p * 5 + k) * 68 + c]);
        cat[(size_t)(pbase + p) * 512 + 64 + c] = m;
    }
    for (int o = t; o < 5120; o += 256) {
        const int r = o >> 6, c = o & 63;
        h2out[(size_t)pbase * 320 + o] = h2s[r * 68 + c];
    }
}

// ---------------------------------------------------------------------------
// Kernel B2: L3 (64->128) + x3max. W3 rows live in REGISTERS (2 couts/thread,
// 32 float4 = 128 VGPR); h2 tile (4 points) in LDS, read wave-uniform
// (broadcast, conflict-free). Writes relu'd h3 to ws, x3 into cat.
// ---------------------------------------------------------------------------
__global__ __launch_bounds__(256) void mlp3_kernel(const float* __restrict__ h2g,
                                                   const float* __restrict__ w3,
                                                   float* __restrict__ h3g,
                                                   float* __restrict__ cat) {
    __shared__ float h2t[4 * 5 * 64];
    const int t = threadIdx.x;
    const int p = t >> 6;            // point within group (wave-uniform)
    const int c0 = (t & 63) * 2;     // two output channels

    float4 wreg[2][16];
    #pragma unroll
    for (int j = 0; j < 2; ++j)
        #pragma unroll
        for (int q4 = 0; q4 < 16; ++q4)
            wreg[j][q4] = *(const float4*)&w3[(size_t)(c0 + j) * 64 + q4 * 4];

    for (int g = blockIdx.x; g < BATCH * NPTS / 4; g += gridDim.x) {
        const size_t base = (size_t)g * 4 * 5 * 64;
        __syncthreads();
        for (int i = t; i < 320; i += 256)
            ((float4*)h2t)[i] = ((const float4*)(h2g + base))[i];
        __syncthreads();

        float acc[2][5] = {};
        const float* hp = h2t + p * 320;
        #pragma unroll
        for (int q4 = 0; q4 < 16; ++q4) {
            float4 hk[5];
            #pragma unroll
            for (int k = 0; k < 5; ++k) hk[k] = *(const float4*)&hp[k * 64 + q4 * 4];
            #pragma unroll
            for (int j = 0; j < 2; ++j)
                #pragma unroll
                for (int k = 0; k < 5; ++k) {
                    acc[j][k] = fmaf(wreg[j][q4].x, hk[k].x, acc[j][k]);
                    acc[j][k] = fmaf(wreg[j][q4].y, hk[k].y, acc[j][k]);
                    acc[j][k] = fmaf(wreg[j][q4].z, hk[k].z, acc[j][k]);
                    acc[j][k] = fmaf(wreg[j][q4].w, hk[k].w, acc[j][k]);
                }
        }
        const int pt = g * 4 + p;
        float m0 = 0.f, m1 = 0.f;  // relu'd values are >= 0
        #pragma unroll
        for (int k = 0; k < 5; ++k) {
            const float v0 = fmaxf(acc[0][k], 0.f);
            const float v1 = fmaxf(acc[1][k], 0.f);
            float2 v = make_float2(v0, v1);
            *(float2*)&h3g[((size_t)pt * 5 + k) * 128 + c0] = v;
            m0 = fmaxf(m0, v0);
            m1 = fmaxf(m1, v1);
        }
        *(float2*)&cat[(size_t)pt * 512 + 128 + c0] = make_float2(m0, m1);
    }
}

// ---------------------------------------------------------------------------
// Kernel C: L4 (128->256) + x4max. W4 row in REGISTERS (1 cout/thread,
// 32 float4 = 128 VGPR); blockIdx.y picks the cout quarter. h3 tile (4 points)
// in LDS, broadcast reads. Writes x4 into cat.
// ---------------------------------------------------------------------------
__global__ __launch_bounds__(256) void mlp4_kernel(const float* __restrict__ h3g,
                                                   const float* __restrict__ w4,
                                                   float* __restrict__ cat) {
    __shared__ float h3t[4 * 5 * 128];
    const int t = threadIdx.x;
    const int p = t >> 6;
    const int c = blockIdx.y * 64 + (t & 63);

    float4 wreg[32];
    #pragma unroll
    for (int q4 = 0; q4 < 32; ++q4)
        wreg[q4] = *(const float4*)&w4[(size_t)c * 128 + q4 * 4];

    for (int g = blockIdx.x; g < BATCH * NPTS / 4; g += gridDim.x) {
        const size_t base = (size_t)g * 4 * 5 * 128;
        __syncthreads();
        for (int i = t; i < 640; i += 256)
            ((float4*)h3t)[i] = ((const float4*)(h3g + base))[i];
        __syncthreads();

        float acc[5] = {};
        const float* hp = h3t + p * 640;
        #pragma unroll
        for (int q4 = 0; q4 < 32; ++q4) {
            #pragma unroll
            for (int k = 0; k < 5; ++k) {
                const float4 h = *(const float4*)&hp[k * 128 + q4 * 4];
                acc[k] = fmaf(wreg[q4].x, h.x, acc[k]);
                acc[k] = fmaf(wreg[q4].y, h.y, acc[k]);
                acc[k] = fmaf(wreg[q4].z, h.z, acc[k]);
                acc[k] = fmaf(wreg[q4].w, h.w, acc[k]);
            }
        }
        float m = 0.f;
        #pragma unroll
        for (int k = 0; k < 5; ++k) m = fmaxf(m, fmaxf(acc[k], 0.f));
        cat[(size_t)(g * 4 + p) * 512 + 256 + c] = m;
    }
}

// ---------------------------------------------------------------------------
// Kernel D: final GEMM out(32768,512) = relu( cat(32768,512) * W5^T ), fp32.
// 64x64 tiles, BK=16, 4x4 microtiles. Rows indexed by tx so the epilogue can
// store float4 along n (coalesced 256B runs per column).
// ---------------------------------------------------------------------------
__global__ __launch_bounds__(256) void gemm512_kernel(const float* __restrict__ cat,
                                                      const float* __restrict__ w5,
                                                      float* __restrict__ out) {
    __shared__ float a_s[16][68];
    __shared__ float w_s[16][68];
    const int t = threadIdx.x;
    const int row0 = blockIdx.x * 64;
    const int col0 = blockIdx.y * 64;
    const int tx = t & 15;   // row micro-tile
    const int ty = t >> 4;   // col micro-tile
    const int lr = t >> 2;         // load row 0..63
    const int lk = (t & 3) * 4;    // load k offset

    float acc[4][4] = {};
    for (int kc = 0; kc < 512; kc += 16) {
        const float4 av = *(const float4*)&cat[(size_t)(row0 + lr) * 512 + kc + lk];
        const float4 wv = *(const float4*)&w5[(size_t)(col0 + lr) * 512 + kc + lk];
        __syncthreads();
        a_s[lk + 0][lr] = av.x; a_s[lk + 1][lr] = av.y;
        a_s[lk + 2][lr] = av.z; a_s[lk + 3][lr] = av.w;
        w_s[lk + 0][lr] = wv.x; w_s[lk + 1][lr] = wv.y;
        w_s[lk + 2][lr] = wv.z; w_s[lk + 3][lr] = wv.w;
        __syncthreads();
        #pragma unroll
        for (int kk = 0; kk < 16; ++kk) {
            const float4 a = *(const float4*)&a_s[kk][tx * 4];
            const float4 w = *(const float4*)&w_s[kk][ty * 4];
            acc[0][0] = fmaf(a.x, w.x, acc[0][0]); acc[0][1] = fmaf(a.x, w.y, acc[0][1]);
            acc[0][2] = fmaf(a.x, w.z, acc[0][2]); acc[0][3] = fmaf(a.x, w.w, acc[0][3]);
            acc[1][0] = fmaf(a.y, w.x, acc[1][0]); acc[1][1] = fmaf(a.y, w.y, acc[1][1]);
            acc[1][2] = fmaf(a.y, w.z, acc[1][2]); acc[1][3] = fmaf(a.y, w.w, acc[1][3]);
            acc[2][0] = fmaf(a.z, w.x, acc[2][0]); acc[2][1] = fmaf(a.z, w.y, acc[2][1]);
            acc[2][2] = fmaf(a.z, w.z, acc[2][2]); acc[2][3] = fmaf(a.z, w.w, acc[2][3]);
            acc[3][0] = fmaf(a.w, w.x, acc[3][0]); acc[3][1] = fmaf(a.w, w.y, acc[3][1]);
            acc[3][2] = fmaf(a.w, w.z, acc[3][2]); acc[3][3] = fmaf(a.w, w.w, acc[3][3]);
        }
    }

    // epilogue: out layout (B, 512, N); rows are n-contiguous via tx
    const int rbase = row0 + tx * 4;
    const int b = rbase >> 13;
    const int nbase = rbase & 8191;
    #pragma unroll
    for (int j = 0; j < 4; ++j) {
        const int col = col0 + ty * 4 + j;
        float4 v = make_float4(fmaxf(acc[0][j], 0.f), fmaxf(acc[1][j], 0.f),
                               fmaxf(acc[2][j], 0.f), fmaxf(acc[3][j], 0.f));
        *(float4*)&out[((size_t)b * 512 + col) * NPTS + nbase] = v;
    }
}

extern "C" void kernel_launch(void* const* d_in, const int* in_sizes, int n_in,
                              void* d_out, int out_size, void* d_ws, size_t ws_size,
                              hipStream_t stream) {
    (void)in_sizes; (void)n_in; (void)out_size; (void)ws_size;
    const float* x  = (const float*)d_in[0];
    const float* w1 = (const float*)d_in[1];
    const float* w2 = (const float*)d_in[2];
    const float* w3 = (const float*)d_in[3];
    const float* w4 = (const float*)d_in[4];
    const float* w5 = (const float*)d_in[5];
    float* out = (float*)d_out;

    // workspace layout
    char* ws = (char*)d_ws;
    int*   idx = (int*)ws;                                   // 4*8192*5*4   = 0.66 MB
    float* cat = (float*)(ws + (1u << 20));                  // 4*8192*512*4 = 64 MB
    float* h3  = (float*)(ws + (1u << 20) + (64u << 20));    // 4*8192*5*128*4 = 80 MB
    float* h2  = out;                                        // scratch: 40 MB <= 64 MB out

    knn_kernel<<<dim3(BATCH * NPTS / 64), dim3(512), 0, stream>>>(x, idx);
    mlp12_kernel<<<dim3(BATCH * NPTS / 16), dim3(256), 0, stream>>>(x, idx, w1, w2, h2, cat);
    mlp3_kernel<<<dim3(256), dim3(256), 0, stream>>>(h2, w3, h3, cat);
    mlp4_kernel<<<dim3(256, 4), dim3(256), 0, stream>>>(h3, w4, cat);
    gemm512_kernel<<<dim3(BATCH * NPTS / 64, 8), dim3(256), 0, stream>>>(cat, w5, out);
}

// Round 4
// 511.821 us; speedup vs baseline: 2.8880x; 1.6896x over previous
//
#include <hip/hip_runtime.h>
#include <cstdint>

#define BATCH 4
#define NPTS  8192
#define KNN   5

typedef short bf16x8 __attribute__((ext_vector_type(8)));
typedef float f32x4  __attribute__((ext_vector_type(4)));
#define MFMA16(a, b, c) __builtin_amdgcn_mfma_f32_16x16x32_bf16((a), (b), (c), 0, 0, 0)

__device__ __forceinline__ unsigned short f2bf(float x) {
    unsigned u = __float_as_uint(x);
    unsigned r = u + 0x7fffu + ((u >> 16) & 1u);   // RN-even
    return (unsigned short)(r >> 16);
}
__device__ __forceinline__ float bf2f(unsigned short h) {
    return __uint_as_float(((unsigned)h) << 16);
}

// ---------------------------------------------------------------------------
// Kernel W: split w3/w4/w5 into bf16 hi/lo pairs (fp32-emulation operands).
// ---------------------------------------------------------------------------
__global__ __launch_bounds__(256) void wsplit_kernel(
        const float* __restrict__ w3, const float* __restrict__ w4,
        const float* __restrict__ w5,
        unsigned short* __restrict__ w3H, unsigned short* __restrict__ w3L,
        unsigned short* __restrict__ w4H, unsigned short* __restrict__ w4L,
        unsigned short* __restrict__ w5H, unsigned short* __restrict__ w5L) {
    const int i = blockIdx.x * 256 + threadIdx.x;   // 303104 total, exact grid
    const float* src; unsigned short *dh, *dl; int off;
    if (i < 8192)       { src = w3; dh = w3H; dl = w3L; off = i; }
    else if (i < 40960) { src = w4; dh = w4H; dl = w4L; off = i - 8192; }
    else                { src = w5; dh = w5H; dl = w5L; off = i - 40960; }
    const float v = src[off];
    const unsigned short hi = f2bf(v);
    dh[off] = hi;
    dl[off] = f2bf(v - bf2f(hi));
}

// ---------------------------------------------------------------------------
// Kernel A: exact 5-NN (unchanged v3). fp32 filter + fp64-exact insert,
// 8 wave-slices, b128 LDS broadcasts, 8-way tie-broken merge.
// ---------------------------------------------------------------------------
__global__ __launch_bounds__(512) void knn_kernel(const float* __restrict__ x,
                                                  int* __restrict__ idx_out) {
    __shared__ alignas(16) float stage[3 * 4096];   // 48 KB
    float* px = stage;
    float* py = stage + 4096;
    float* pz = stage + 8192;

    const int t = threadIdx.x;
    const int q = t & 63;
    const int w = t >> 6;
    const int b = blockIdx.x >> 7;
    const int qg = (blockIdx.x & 127) * 64 + q;
    const float* xb = x + (size_t)b * 3 * NPTS;

    const float qx = xb[qg];
    const float qy = xb[NPTS + qg];
    const float qz = xb[2 * NPTS + qg];

    double d0 = -1e300, d1 = -1e300, d2 = -1e300, d3 = -1e300, d4 = -1e300;
    int i0 = 0, i1 = 0, i2 = 0, i3 = 0, i4 = 0;
    float thr = -3.0e38f;

    for (int half = 0; half < 2; ++half) {
        const int base = half * 4096;
        __syncthreads();
        {
            const float4* gx = (const float4*)(xb + base);
            const float4* gy = (const float4*)(xb + NPTS + base);
            const float4* gz = (const float4*)(xb + 2 * NPTS + base);
            for (int i = t; i < 1024; i += 512) {
                ((float4*)px)[i] = gx[i];
                ((float4*)py)[i] = gy[i];
                ((float4*)pz)[i] = gz[i];
            }
        }
        __syncthreads();
        const int glo = w * 128;
        #pragma unroll 2
        for (int g = glo; g < glo + 128; ++g) {
            const float4 fx4 = ((const float4*)px)[g];
            const float4 fy4 = ((const float4*)py)[g];
            const float4 fz4 = ((const float4*)pz)[g];
            float d32[4];
            {
                const float dx = qx - fx4.x, dy = qy - fy4.x, dz = qz - fz4.x;
                d32[0] = -fmaf(dz, dz, fmaf(dy, dy, dx * dx));
            }
            {
                const float dx = qx - fx4.y, dy = qy - fy4.y, dz = qz - fz4.y;
                d32[1] = -fmaf(dz, dz, fmaf(dy, dy, dx * dx));
            }
            {
                const float dx = qx - fx4.z, dy = qy - fy4.z, dz = qz - fz4.z;
                d32[2] = -fmaf(dz, dz, fmaf(dy, dy, dx * dx));
            }
            {
                const float dx = qx - fx4.w, dy = qy - fy4.w, dz = qz - fz4.w;
                d32[3] = -fmaf(dz, dz, fmaf(dy, dy, dx * dx));
            }
            const float dmax = fmaxf(fmaxf(d32[0], d32[1]), fmaxf(d32[2], d32[3]));
            if (dmax > thr) {
                const float fxs[4] = {fx4.x, fx4.y, fx4.z, fx4.w};
                const float fys[4] = {fy4.x, fy4.y, fy4.z, fy4.w};
                const float fzs[4] = {fz4.x, fz4.y, fz4.z, fz4.w};
                #pragma unroll
                for (int j = 0; j < 4; ++j) {
                    if (d32[j] > thr) {
                        const double ddx = (double)qx - (double)fxs[j];
                        const double ddy = (double)qy - (double)fys[j];
                        const double ddz = (double)qz - (double)fzs[j];
                        const double dd = -(ddx * ddx + ddy * ddy + ddz * ddz);
                        const int mm = base + g * 4 + j;
                        if (dd > d4) {
                            if (dd > d3) {
                                d4 = d3; i4 = i3;
                                if (dd > d2) {
                                    d3 = d2; i3 = i2;
                                    if (dd > d1) {
                                        d2 = d1; i2 = i1;
                                        if (dd > d0) { d1 = d0; i1 = i0; d0 = dd; i0 = mm; }
                                        else         { d1 = dd; i1 = mm; }
                                    } else { d2 = dd; i2 = mm; }
                                } else { d3 = dd; i3 = mm; }
                            } else { d4 = dd; i4 = mm; }
                            thr = (float)d4 - 1e-3f;
                        }
                    }
                }
            }
        }
    }

    __syncthreads();
    double* dm = (double*)stage;
    int*    im = (int*)(stage + 5120);
    const int e = (w * 64 + q) * 5;
    dm[e + 0] = d0; dm[e + 1] = d1; dm[e + 2] = d2; dm[e + 3] = d3; dm[e + 4] = d4;
    im[e + 0] = i0; im[e + 1] = i1; im[e + 2] = i2; im[e + 3] = i3; im[e + 4] = i4;
    __syncthreads();

    if (t < 64) {
        int    cur[8] = {0, 0, 0, 0, 0, 0, 0, 0};
        double hd[8];
        int    hi[8];
        #pragma unroll
        for (int ww = 0; ww < 8; ++ww) {
            hd[ww] = dm[(ww * 64 + t) * 5];
            hi[ww] = im[(ww * 64 + t) * 5];
        }
        int* o = idx_out + ((size_t)b * NPTS + (blockIdx.x & 127) * 64 + t) * KNN;
        #pragma unroll
        for (int r = 0; r < KNN; ++r) {
            int wbest = 0;
            #pragma unroll
            for (int ww = 1; ww < 8; ++ww) {
                const bool better = (hd[ww] > hd[wbest]) ||
                                    (hd[ww] == hd[wbest] && hi[ww] < hi[wbest]);
                if (better) wbest = ww;
            }
            o[r] = hi[wbest];
            const int c = ++cur[wbest];
            if (c < KNN) {
                hd[wbest] = dm[(wbest * 64 + t) * 5 + c];
                hi[wbest] = im[(wbest * 64 + t) * 5 + c];
            } else {
                hd[wbest] = -1e301;
                hi[wbest] = 0x7fffffff;
            }
        }
    }
}

// ---------------------------------------------------------------------------
// Kernel B1: gather + L1 (6->64) + x1max + L2 (64->64) + x2max (fp32 compute).
// Epilogue now writes h2 as interleaved bf16 hi|lo rows (d_out scratch) and
// x1/x2 into catH/catL.
// ---------------------------------------------------------------------------
__global__ __launch_bounds__(256) void mlp12_kernel(const float* __restrict__ x,
                                                    const int* __restrict__ idx,
                                                    const float* __restrict__ w1,
                                                    const float* __restrict__ w2,
                                                    unsigned short* __restrict__ h2HL,
                                                    unsigned short* __restrict__ catH,
                                                    unsigned short* __restrict__ catL) {
    __shared__ float w1s[64 * 6];
    __shared__ float w2s[64 * 68];
    __shared__ float fbuf[80][6];
    __shared__ float h1s[80 * 68];
    __shared__ float h2s[80 * 68];
    const int t = threadIdx.x;
    const int pbase = blockIdx.x * 16;

    for (int i = t; i < 384; i += 256) w1s[i] = w1[i];
    for (int i = t; i < 4096; i += 256) {
        int c = i >> 6, q = i & 63;
        w2s[c * 68 + q] = w2[i];
    }
    if (t < 80) {
        const int pt = pbase + t / 5;
        const int b = pt >> 13;
        const int n = pt & 8191;
        const int k = t % 5;
        const int j = idx[(size_t)pt * KNN + k];
        const float* xb = x + (size_t)b * 3 * NPTS;
        fbuf[t][0] = xb[j];
        fbuf[t][1] = xb[NPTS + j];
        fbuf[t][2] = xb[2 * NPTS + j];
        fbuf[t][3] = xb[n];
        fbuf[t][4] = xb[NPTS + n];
        fbuf[t][5] = xb[2 * NPTS + n];
    }
    __syncthreads();

    for (int o = t; o < 5120; o += 256) {
        const int r = o >> 6, c = o & 63;
        float acc = 0.f;
        #pragma unroll
        for (int q = 0; q < 6; ++q) acc = fmaf(w1s[c * 6 + q], fbuf[r][q], acc);
        h1s[r * 68 + c] = fmaxf(acc, 0.f);
    }
    __syncthreads();

    for (int o = t; o < 1024; o += 256) {
        const int p = o >> 6, c = o & 63;
        float m = h1s[(p * 5) * 68 + c];
        #pragma unroll
        for (int k = 1; k < 5; ++k) m = fmaxf(m, h1s[(p * 5 + k) * 68 + c]);
        const unsigned short hi = f2bf(m);
        const size_t co = (size_t)(pbase + p) * 512 + c;
        catH[co] = hi;
        catL[co] = f2bf(m - bf2f(hi));
    }

    for (int tile = t; tile < 320; tile += 256) {
        const int r0 = (tile % 20) * 4;
        const int c0 = (tile / 20) * 4;
        float acc[4][4] = {};
        for (int q = 0; q < 64; q += 4) {
            float4 a[4], w[4];
            #pragma unroll
            for (int i = 0; i < 4; ++i) a[i] = *(const float4*)&h1s[(r0 + i) * 68 + q];
            #pragma unroll
            for (int j = 0; j < 4; ++j) w[j] = *(const float4*)&w2s[(c0 + j) * 68 + q];
            #pragma unroll
            for (int i = 0; i < 4; ++i)
                #pragma unroll
                for (int j = 0; j < 4; ++j) {
                    acc[i][j] = fmaf(a[i].x, w[j].x, acc[i][j]);
                    acc[i][j] = fmaf(a[i].y, w[j].y, acc[i][j]);
                    acc[i][j] = fmaf(a[i].z, w[j].z, acc[i][j]);
                    acc[i][j] = fmaf(a[i].w, w[j].w, acc[i][j]);
                }
        }
        #pragma unroll
        for (int i = 0; i < 4; ++i)
            #pragma unroll
            for (int j = 0; j < 4; ++j)
                h2s[(r0 + i) * 68 + c0 + j] = fmaxf(acc[i][j], 0.f);
    }
    __syncthreads();

    for (int o = t; o < 1024; o += 256) {
        const int p = o >> 6, c = o & 63;
        float m = h2s[(p * 5) * 68 + c];
        #pragma unroll
        for (int k = 1; k < 5; ++k) m = fmaxf(m, h2s[(p * 5 + k) * 68 + c]);
        const unsigned short hi = f2bf(m);
        const size_t co = (size_t)(pbase + p) * 512 + 64 + c;
        catH[co] = hi;
        catL[co] = f2bf(m - bf2f(hi));
    }
    for (int o = t; o < 5120; o += 256) {
        const int r = o >> 6, c = o & 63;
        const float v = h2s[r * 68 + c];
        const unsigned short hi = f2bf(v);
        const size_t rowb = (size_t)(pbase * 5 + r) * 128;
        h2HL[rowb + c]      = hi;
        h2HL[rowb + 64 + c] = f2bf(v - bf2f(hi));
    }
}

// ---------------------------------------------------------------------------
// Kernel B2: L3 (64->128) via split-bf16 MFMA + x3max.
// Block: 80 rows (16 points), N=128, K=64. Writes h3H (ws), h3L (in-place
// over h2HL in d_out), catH/catL cols [128,256).
// ---------------------------------------------------------------------------
__global__ __launch_bounds__(256) void mlp3_kernel(
        const unsigned short* __restrict__ h2HL,
        const unsigned short* __restrict__ w3H, const unsigned short* __restrict__ w3L,
        unsigned short* __restrict__ h3H, unsigned short* __restrict__ h3L,
        unsigned short* __restrict__ catH, unsigned short* __restrict__ catL) {
    __shared__ __align__(16) char smem[59904];
    unsigned short* aH = (unsigned short*)smem;            // [80][72]
    unsigned short* aL = aH + 80 * 72;                     // @11520B
    unsigned short* bH = (unsigned short*)(smem + 23040);  // [128][72]
    unsigned short* bL = (unsigned short*)(smem + 41472);

    const int t = threadIdx.x;
    const int R0 = blockIdx.x * 80;
    const int P0 = blockIdx.x * 16;

    for (int c = t; c < 1280; c += 256) {                  // A: h2 hi|lo rows
        const int row = c >> 4, seg = c & 15;
        const uint4 v = *(const uint4*)(h2HL + (size_t)(R0 + row) * 128 + seg * 8);
        *(uint4*)((seg < 8 ? aH : aL) + row * 72 + (seg & 7) * 8) = v;
    }
    for (int c = t; c < 1024; c += 256) {                  // B hi
        const int row = c >> 3, seg = c & 7;
        *(uint4*)(bH + row * 72 + seg * 8) =
            *(const uint4*)(w3H + row * 64 + seg * 8);
    }
    for (int c = t; c < 1024; c += 256) {                  // B lo
        const int row = c >> 3, seg = c & 7;
        *(uint4*)(bL + row * 72 + seg * 8) =
            *(const uint4*)(w3L + row * 64 + seg * 8);
    }
    __syncthreads();

    const int w = t >> 6, lane = t & 63;
    const int q = lane >> 4, l16 = lane & 15;
    const int n0 = w * 32;

    f32x4 acc[5][2];
    #pragma unroll
    for (int mt = 0; mt < 5; ++mt)
        #pragma unroll
        for (int nt = 0; nt < 2; ++nt)
            acc[mt][nt] = (f32x4){0.f, 0.f, 0.f, 0.f};

    #pragma unroll
    for (int kt = 0; kt < 2; ++kt) {
        const int k0 = kt * 32 + q * 8;
        bf16x8 bh[2], bl[2];
        #pragma unroll
        for (int nt = 0; nt < 2; ++nt) {
            bh[nt] = *(const bf16x8*)(bH + (n0 + nt * 16 + l16) * 72 + k0);
            bl[nt] = *(const bf16x8*)(bL + (n0 + nt * 16 + l16) * 72 + k0);
        }
        #pragma unroll
        for (int mt = 0; mt < 5; ++mt) {
            const bf16x8 ah = *(const bf16x8*)(aH + (mt * 16 + l16) * 72 + k0);
            const bf16x8 al = *(const bf16x8*)(aL + (mt * 16 + l16) * 72 + k0);
            #pragma unroll
            for (int nt = 0; nt < 2; ++nt) {
                acc[mt][nt] = MFMA16(ah, bh[nt], acc[mt][nt]);
                acc[mt][nt] = MFMA16(ah, bl[nt], acc[mt][nt]);
                acc[mt][nt] = MFMA16(al, bh[nt], acc[mt][nt]);
            }
        }
    }

    __syncthreads();                       // A/B staging dead; alias Dbuf
    float* Dbuf = (float*)smem;            // [80][132] fp32
    #pragma unroll
    for (int mt = 0; mt < 5; ++mt)
        #pragma unroll
        for (int nt = 0; nt < 2; ++nt)
            #pragma unroll
            for (int r = 0; r < 4; ++r)
                Dbuf[(mt * 16 + q * 4 + r) * 132 + n0 + nt * 16 + l16] =
                    fmaxf(acc[mt][nt][r], 0.f);
    __syncthreads();

    {
        const int col = t & 127;
        const int p0 = (t >> 7) * 8;
        #pragma unroll
        for (int p = 0; p < 8; ++p) {
            const int pp = p0 + p;
            float mx = 0.f;
            #pragma unroll
            for (int k = 0; k < 5; ++k) {
                const int row = pp * 5 + k;
                const float v = Dbuf[row * 132 + col];
                const unsigned short hi = f2bf(v);
                const unsigned short lo = f2bf(v - bf2f(hi));
                const size_t off = (size_t)(R0 + row) * 128 + col;
                h3H[off] = hi;
                h3L[off] = lo;
                mx = fmaxf(mx, bf2f(hi) + bf2f(lo));
            }
            const unsigned short mh = f2bf(mx);
            const size_t co = (size_t)(P0 + pp) * 512 + 128 + col;
            catH[co] = mh;
            catL[co] = f2bf(mx - bf2f(mh));
        }
    }
}

// ---------------------------------------------------------------------------
// Kernel C: L4 (128->256) via split-bf16 MFMA + x4max.
// Block: 80 rows (16 points), N=128 (blockIdx.y half), K=128 (4 k-steps).
// Writes catH/catL cols [256,512).
// ---------------------------------------------------------------------------
__global__ __launch_bounds__(256) void mlp4_kernel(
        const unsigned short* __restrict__ h3H, const unsigned short* __restrict__ h3L,
        const unsigned short* __restrict__ w4H, const unsigned short* __restrict__ w4L,
        unsigned short* __restrict__ catH, unsigned short* __restrict__ catL) {
    __shared__ __align__(16) char smem[64000];
    unsigned short* aH = (unsigned short*)smem;            // [80][136]
    unsigned short* aL = aH + 80 * 136;                    // @21760B
    unsigned short* bH = (unsigned short*)(smem + 43520);  // [128][40] per k-step
    unsigned short* bL = (unsigned short*)(smem + 53760);

    const int t = threadIdx.x;
    const int R0 = blockIdx.x * 80;
    const int P0 = blockIdx.x * 16;
    const int ny = blockIdx.y;                             // cout half

    for (int c = t; c < 1280; c += 256) {                  // A hi
        const int row = c >> 4, seg = c & 15;
        *(uint4*)(aH + row * 136 + seg * 8) =
            *(const uint4*)(h3H + (size_t)(R0 + row) * 128 + seg * 8);
    }
    for (int c = t; c < 1280; c += 256) {                  // A lo
        const int row = c >> 4, seg = c & 15;
        *(uint4*)(aL + row * 136 + seg * 8) =
            *(const uint4*)(h3L + (size_t)(R0 + row) * 128 + seg * 8);
    }

    const int w = t >> 6, lane = t & 63;
    const int q = lane >> 4, l16 = lane & 15;
    const int n0 = w * 32;

    f32x4 acc[5][2];
    #pragma unroll
    for (int mt = 0; mt < 5; ++mt)
        #pragma unroll
        for (int nt = 0; nt < 2; ++nt)
            acc[mt][nt] = (f32x4){0.f, 0.f, 0.f, 0.f};

    for (int ks = 0; ks < 4; ++ks) {
        __syncthreads();
        #pragma unroll
        for (int i = 0; i < 2; ++i) {                      // B hi: 512 chunks
            const int c = t + i * 256;
            const int row = c >> 2, seg = c & 3;
            *(uint4*)(bH + row * 40 + seg * 8) =
                *(const uint4*)(w4H + (size_t)(ny * 128 + row) * 128 + ks * 32 + seg * 8);
        }
        #pragma unroll
        for (int i = 0; i < 2; ++i) {                      // B lo
            const int c = t + i * 256;
            const int row = c >> 2, seg = c & 3;
            *(uint4*)(bL + row * 40 + seg * 8) =
                *(const uint4*)(w4L + (size_t)(ny * 128 + row) * 128 + ks * 32 + seg * 8);
        }
        __syncthreads();

        const int k0 = ks * 32 + q * 8;
        const int kb = q * 8;
        bf16x8 bh[2], bl[2];
        #pragma unroll
        for (int nt = 0; nt < 2; ++nt) {
            bh[nt] = *(const bf16x8*)(bH + (n0 + nt * 16 + l16) * 40 + kb);
            bl[nt] = *(const bf16x8*)(bL + (n0 + nt * 16 + l16) * 40 + kb);
        }
        #pragma unroll
        for (int mt = 0; mt < 5; ++mt) {
            const bf16x8 ah = *(const bf16x8*)(aH + (mt * 16 + l16) * 136 + k0);
            const bf16x8 al = *(const bf16x8*)(aL + (mt * 16 + l16) * 136 + k0);
            #pragma unroll
            for (int nt = 0; nt < 2; ++nt) {
                acc[mt][nt] = MFMA16(ah, bh[nt], acc[mt][nt]);
                acc[mt][nt] = MFMA16(ah, bl[nt], acc[mt][nt]);
                acc[mt][nt] = MFMA16(al, bh[nt], acc[mt][nt]);
            }
        }
    }

    __syncthreads();
    float* Dbuf = (float*)smem;            // [80][132] fp32
    #pragma unroll
    for (int mt = 0; mt < 5; ++mt)
        #pragma unroll
        for (int nt = 0; nt < 2; ++nt)
            #pragma unroll
            for (int r = 0; r < 4; ++r)
                Dbuf[(mt * 16 + q * 4 + r) * 132 + n0 + nt * 16 + l16] =
                    fmaxf(acc[mt][nt][r], 0.f);
    __syncthreads();

    {
        const int col = t & 127;
        const int p0 = (t >> 7) * 8;
        const int cout = 256 + ny * 128 + col;
        #pragma unroll
        for (int p = 0; p < 8; ++p) {
            const int pp = p0 + p;
            float mx = 0.f;
            #pragma unroll
            for (int k = 0; k < 5; ++k)
                mx = fmaxf(mx, Dbuf[(pp * 5 + k) * 132 + col]);
            const unsigned short mh = f2bf(mx);
            const size_t co = (size_t)(P0 + pp) * 512 + cout;
            catH[co] = mh;
            catL[co] = f2bf(mx - bf2f(mh));
        }
    }
}

// ---------------------------------------------------------------------------
// Kernel D: final GEMM out = relu(cat(32768x512) * W5^T) via split-bf16 MFMA.
// 128x128 tiles, K=512 in 16 k-steps. Band-wise LDS epilogue for coalesced
// (B,512,N)-layout stores.
// ---------------------------------------------------------------------------
__global__ __launch_bounds__(256) void gemm512_kernel(
        const unsigned short* __restrict__ catH, const unsigned short* __restrict__ catL,
        const unsigned short* __restrict__ w5H, const unsigned short* __restrict__ w5L,
        float* __restrict__ out) {
    __shared__ __align__(16) char smem[40960];
    unsigned short* aH = (unsigned short*)smem;            // [128][40]
    unsigned short* aL = aH + 128 * 40;                    // @10240B
    unsigned short* bH = (unsigned short*)(smem + 20480);
    unsigned short* bL = (unsigned short*)(smem + 30720);

    const int t = threadIdx.x;
    const int m0 = blockIdx.x * 128;
    const int n0blk = blockIdx.y * 128;

    const int w = t >> 6, lane = t & 63;
    const int q = lane >> 4, l16 = lane & 15;
    const int m_off = (w >> 1) * 64;
    const int n_off = (w & 1) * 64;

    f32x4 acc[4][4];
    #pragma unroll
    for (int mt = 0; mt < 4; ++mt)
        #pragma unroll
        for (int nt = 0; nt < 4; ++nt)
            acc[mt][nt] = (f32x4){0.f, 0.f, 0.f, 0.f};

    for (int kc = 0; kc < 512; kc += 32) {
        __syncthreads();
        #pragma unroll
        for (int i = 0; i < 2; ++i) {
            const int c = t + i * 256;
            const int row = c >> 2, seg = c & 3;
            *(uint4*)(aH + row * 40 + seg * 8) =
                *(const uint4*)(catH + (size_t)(m0 + row) * 512 + kc + seg * 8);
        }
        #pragma unroll
        for (int i = 0; i < 2; ++i) {
            const int c = t + i * 256;
            const int row = c >> 2, seg = c & 3;
            *(uint4*)(aL + row * 40 + seg * 8) =
                *(const uint4*)(catL + (size_t)(m0 + row) * 512 + kc + seg * 8);
        }
        #pragma unroll
        for (int i = 0; i < 2; ++i) {
            const int c = t + i * 256;
            const int row = c >> 2, seg = c & 3;
            *(uint4*)(bH + row * 40 + seg * 8) =
                *(const uint4*)(w5H + (size_t)(n0blk + row) * 512 + kc + seg * 8);
        }
        #pragma unroll
        for (int i = 0; i < 2; ++i) {
            const int c = t + i * 256;
            const int row = c >> 2, seg = c & 3;
            *(uint4*)(bL + row * 40 + seg * 8) =
                *(const uint4*)(w5L + (size_t)(n0blk + row) * 512 + kc + seg * 8);
        }
        __syncthreads();

        const int k0 = q * 8;
        bf16x8 bh[4], bl[4];
        #pragma unroll
        for (int nt = 0; nt < 4; ++nt) {
            bh[nt] = *(const bf16x8*)(bH + (n_off + nt * 16 + l16) * 40 + k0);
            bl[nt] = *(const bf16x8*)(bL + (n_off + nt * 16 + l16) * 40 + k0);
        }
        #pragma unroll
        for (int mt = 0; mt < 4; ++mt) {
            const bf16x8 ah = *(const bf16x8*)(aH + (m_off + mt * 16 + l16) * 40 + k0);
            const bf16x8 al = *(const bf16x8*)(aL + (m_off + mt * 16 + l16) * 40 + k0);
            #pragma unroll
            for (int nt = 0; nt < 4; ++nt) {
                acc[mt][nt] = MFMA16(ah, bh[nt], acc[mt][nt]);
                acc[mt][nt] = MFMA16(ah, bl[nt], acc[mt][nt]);
                acc[mt][nt] = MFMA16(al, bh[nt], acc[mt][nt]);
            }
        }
    }

    // band-wise epilogue: 8 bands of 16 rows; LDS transpose for coalesced out
    float* bandbuf = (float*)smem;         // [16][132] fp32
    for (int b8 = 0; b8 < 8; ++b8) {
        __syncthreads();
        if ((w >> 1) == (b8 >> 2)) {
            const int mt = b8 & 3;
            #pragma unroll
            for (int nt = 0; nt < 4; ++nt)
                #pragma unroll
                for (int r = 0; r < 4; ++r)
                    bandbuf[(q * 4 + r) * 132 + n_off + nt * 16 + l16] =
                        fmaxf(acc[mt][nt][r], 0.f);
        }
        __syncthreads();
        const int col = t >> 1;
        const int ph = (t & 1) * 8;
        const int P = m0 + b8 * 16 + ph;
        const int bb = P >> 13, nn = P & 8191;
        const int cout = n0blk + col;
        float tmp[8];
        #pragma unroll
        for (int j = 0; j < 8; ++j) tmp[j] = bandbuf[(ph + j) * 132 + col];
        float* op = &out[((size_t)bb * 512 + cout) * NPTS + nn];
        *(float4*)op       = make_float4(tmp[0], tmp[1], tmp[2], tmp[3]);
        *(float4*)(op + 4) = make_float4(tmp[4], tmp[5], tmp[6], tmp[7]);
    }
}

extern "C" void kernel_launch(void* const* d_in, const int* in_sizes, int n_in,
                              void* d_out, int out_size, void* d_ws, size_t ws_size,
                              hipStream_t stream) {
    (void)in_sizes; (void)n_in; (void)out_size; (void)ws_size;
    const float* x  = (const float*)d_in[0];
    const float* w1 = (const float*)d_in[1];
    const float* w2 = (const float*)d_in[2];
    const float* w3 = (const float*)d_in[3];
    const float* w4 = (const float*)d_in[4];
    const float* w5 = (const float*)d_in[5];
    float* out = (float*)d_out;

    // workspace layout (111.2 MB total, < proven 145 MB)
    char* ws = (char*)d_ws;
    unsigned short* w3H = (unsigned short*)(ws + 0);          //  16384 B
    unsigned short* w3L = (unsigned short*)(ws + 16384);
    unsigned short* w4H = (unsigned short*)(ws + 32768);      //  65536 B
    unsigned short* w4L = (unsigned short*)(ws + 98304);
    unsigned short* w5H = (unsigned short*)(ws + 163840);     // 524288 B
    unsigned short* w5L = (unsigned short*)(ws + 688128);
    int*            idx = (int*)(ws + 1212416);               // 655360 B
    unsigned short* catH = (unsigned short*)(ws + 2097152);   // 33.55 MB
    unsigned short* catL = (unsigned short*)(ws + 35651584);  // 33.55 MB
    unsigned short* h3H  = (unsigned short*)(ws + 69206016);  // 41.94 MB
    // d_out doubles as scratch: h2 (hi|lo interleaved) then h3L in-place
    unsigned short* h2HL = (unsigned short*)d_out;
    unsigned short* h3L  = (unsigned short*)d_out;

    wsplit_kernel<<<dim3(1184), dim3(256), 0, stream>>>(w3, w4, w5,
                                                        w3H, w3L, w4H, w4L, w5H, w5L);
    knn_kernel<<<dim3(BATCH * NPTS / 64), dim3(512), 0, stream>>>(x, idx);
    mlp12_kernel<<<dim3(BATCH * NPTS / 16), dim3(256), 0, stream>>>(x, idx, w1, w2,
                                                                    h2HL, catH, catL);
    mlp3_kernel<<<dim3(BATCH * NPTS * KNN / 80), dim3(256), 0, stream>>>(
        h2HL, w3H, w3L, h3H, h3L, catH, catL);
    mlp4_kernel<<<dim3(BATCH * NPTS * KNN / 80, 2), dim3(256), 0, stream>>>(
        h3H, h3L, w4H, w4L, catH, catL);
    gemm512_kernel<<<dim3(BATCH * NPTS / 128, 4), dim3(256), 0, stream>>>(
        catH, catL, w5H, w5L, out);
}

// Round 5
// 491.927 us; speedup vs baseline: 3.0048x; 1.0404x over previous
//
#include <hip/hip_runtime.h>
#include <cstdint>

#define BATCH 4
#define NPTS  8192
#define KNN   5
#define CAPQ  64

typedef short bf16x8 __attribute__((ext_vector_type(8)));
typedef float f32x4  __attribute__((ext_vector_type(4)));
#define MFMA16(a, b, c) __builtin_amdgcn_mfma_f32_16x16x32_bf16((a), (b), (c), 0, 0, 0)

__device__ __forceinline__ unsigned short f2bf(float x) {
    unsigned u = __float_as_uint(x);
    unsigned r = u + 0x7fffu + ((u >> 16) & 1u);   // RN-even
    return (unsigned short)(r >> 16);
}
__device__ __forceinline__ float bf2f(unsigned short h) {
    return __uint_as_float(((unsigned)h) << 16);
}

// ---------------------------------------------------------------------------
// Kernel W: split w3/w4/w5 into bf16 hi/lo pairs (fp32-emulation operands).
// ---------------------------------------------------------------------------
__global__ __launch_bounds__(256) void wsplit_kernel(
        const float* __restrict__ w3, const float* __restrict__ w4,
        const float* __restrict__ w5,
        unsigned short* __restrict__ w3H, unsigned short* __restrict__ w3L,
        unsigned short* __restrict__ w4H, unsigned short* __restrict__ w4L,
        unsigned short* __restrict__ w5H, unsigned short* __restrict__ w5L) {
    const int i = blockIdx.x * 256 + threadIdx.x;   // 303104 total, exact grid
    const float* src; unsigned short *dh, *dl; int off;
    if (i < 8192)       { src = w3; dh = w3H; dl = w3L; off = i; }
    else if (i < 40960) { src = w4; dh = w4H; dl = w4L; off = i - 8192; }
    else                { src = w5; dh = w5H; dl = w5L; off = i - 40960; }
    const float v = src[off];
    const unsigned short hi = f2bf(v);
    dh[off] = hi;
    dl[off] = f2bf(v - bf2f(hi));
}

// ---------------------------------------------------------------------------
// Kernel A: exact 5-NN, v4 (divergence-free structure).
// Pass A: per-wave slice scan, branchless value-only fp32 top-5 (fmed3 chain).
// Cross-slice min + 1e-4 margin -> per-query threshold (global rank <= 37 by
// pigeonhole over 8 slices; fp32 dist error ~1e-5 << margin).
// Pass B: rescan, compact accepted indices into per-query LDS list (atomic).
// Pass C: exact fp64 re-rank of finalists, (d,idx)-lexicographic rank ->
// top_k tie-break semantics. Candidate coords read wave-uniform from global
// (L2-resident, scalar-load path) -- no LDS staging at all.
// ---------------------------------------------------------------------------
__global__ __launch_bounds__(512) void knn_kernel(const float* __restrict__ x,
                                                  int* __restrict__ idx_out) {
    __shared__ float  thrA[8 * 64];     //  2 KB: per (slice, query) 5th
    __shared__ float  thrQ[64];         //  per-query threshold
    __shared__ int    qcnt[64];
    __shared__ int    qidx[64 * CAPQ];  // 16 KB finalist indices
    __shared__ double qd[64 * CAPQ];    // 32 KB finalist exact distances

    const int t = threadIdx.x;
    const int lane = t & 63;            // query lane
    const int s = t >> 6;               // slice 0..7 (wave-uniform)
    const int b = blockIdx.x >> 7;
    const int q0 = (blockIdx.x & 127) * 64;
    const int qg = q0 + lane;
    const float* xb = x + (size_t)b * 3 * NPTS;

    const float qx = xb[qg];
    const float qy = xb[NPTS + qg];
    const float qz = xb[2 * NPTS + qg];

    if (t < 64) qcnt[t] = 0;

    const float4* gx = (const float4*)xb;
    const float4* gy = (const float4*)(xb + NPTS);
    const float4* gz = (const float4*)(xb + 2 * NPTS);
    const int g0 = s * 256;             // 256 float4-groups = 1024 candidates

    // ---- Pass A: branchless value-only top-5 (positive dist^2, keep smallest)
    float s0 = 3e38f, s1 = 3e38f, s2 = 3e38f, s3 = 3e38f, s4 = 3e38f;
    #pragma unroll 2
    for (int g = g0; g < g0 + 256; ++g) {
        const float4 fx = gx[g], fy = gy[g], fz = gz[g];
        float d[4];
        {
            const float dx = qx - fx.x, dy = qy - fy.x, dz = qz - fz.x;
            d[0] = fmaf(dz, dz, fmaf(dy, dy, dx * dx));
        }
        {
            const float dx = qx - fx.y, dy = qy - fy.y, dz = qz - fz.y;
            d[1] = fmaf(dz, dz, fmaf(dy, dy, dx * dx));
        }
        {
            const float dx = qx - fx.z, dy = qy - fy.z, dz = qz - fz.z;
            d[2] = fmaf(dz, dz, fmaf(dy, dy, dx * dx));
        }
        {
            const float dx = qx - fx.w, dy = qy - fy.w, dz = qz - fz.w;
            d[3] = fmaf(dz, dz, fmaf(dy, dy, dx * dx));
        }
        #pragma unroll
        for (int j = 0; j < 4; ++j) {
            const float dj = d[j];
            s4 = __builtin_amdgcn_fmed3f(s3, dj, s4);
            s3 = __builtin_amdgcn_fmed3f(s2, dj, s3);
            s2 = __builtin_amdgcn_fmed3f(s1, dj, s2);
            s1 = __builtin_amdgcn_fmed3f(s0, dj, s1);
            s0 = fminf(s0, dj);
        }
    }
    thrA[s * 64 + lane] = s4;
    __syncthreads();
    if (t < 64) {
        float m = thrA[t];
        #pragma unroll
        for (int ww = 1; ww < 8; ++ww) m = fminf(m, thrA[ww * 64 + t]);
        thrQ[t] = m + 1e-4f;
    }
    __syncthreads();

    // ---- Pass B: compact accepted candidate indices per query ----
    const float thrq = thrQ[lane];
    #pragma unroll 2
    for (int g = g0; g < g0 + 256; ++g) {
        const float4 fx = gx[g], fy = gy[g], fz = gz[g];
        float d[4];
        {
            const float dx = qx - fx.x, dy = qy - fy.x, dz = qz - fz.x;
            d[0] = fmaf(dz, dz, fmaf(dy, dy, dx * dx));
        }
        {
            const float dx = qx - fx.y, dy = qy - fy.y, dz = qz - fz.y;
            d[1] = fmaf(dz, dz, fmaf(dy, dy, dx * dx));
        }
        {
            const float dx = qx - fx.z, dy = qy - fy.z, dz = qz - fz.z;
            d[2] = fmaf(dz, dz, fmaf(dy, dy, dx * dx));
        }
        {
            const float dx = qx - fx.w, dy = qy - fy.w, dz = qz - fz.w;
            d[3] = fmaf(dz, dz, fmaf(dy, dy, dx * dx));
        }
        const float dmin = fminf(fminf(d[0], d[1]), fminf(d[2], d[3]));
        if (dmin < thrq) {
            #pragma unroll
            for (int j = 0; j < 4; ++j) {
                if (d[j] < thrq) {
                    const int slot = atomicAdd(&qcnt[lane], 1);
                    if (slot < CAPQ) qidx[lane * CAPQ + slot] = g * 4 + j;
                }
            }
        }
    }
    __syncthreads();

    // ---- Pass C: exact fp64 distances + lexicographic rank select ----
    const int ql = t >> 3;                // 64 queries x 8 threads
    const int jt = t & 7;
    const int cnt = min(qcnt[ql], CAPQ);
    const double Qx = (double)xb[q0 + ql];
    const double Qy = (double)xb[NPTS + q0 + ql];
    const double Qz = (double)xb[2 * NPTS + q0 + ql];
    for (int j = jt; j < cnt; j += 8) {
        const int ci = qidx[ql * CAPQ + j];
        const double ddx = Qx - (double)xb[ci];
        const double ddy = Qy - (double)xb[NPTS + ci];
        const double ddz = Qz - (double)xb[2 * NPTS + ci];
        qd[ql * CAPQ + j] = ddx * ddx + ddy * ddy + ddz * ddz;
    }
    __syncthreads();
    for (int j = jt; j < cnt; j += 8) {
        const double dj = qd[ql * CAPQ + j];
        const int    ij = qidx[ql * CAPQ + j];
        int rank = 0;
        for (int k = 0; k < cnt; ++k) {
            const double dk = qd[ql * CAPQ + k];
            const int    ik = qidx[ql * CAPQ + k];
            rank += (dk < dj) || (dk == dj && ik < ij);
        }
        if (rank < KNN)
            idx_out[((size_t)b * NPTS + q0 + ql) * KNN + rank] = ij;
    }
}

// ---------------------------------------------------------------------------
// Kernel B1: gather + L1 (6->64) + x1max + L2 (64->64) + x2max (fp32 compute).
// Epilogue writes h2 as interleaved bf16 hi|lo rows (d_out scratch) and
// x1/x2 into catH/catL.
// ---------------------------------------------------------------------------
__global__ __launch_bounds__(256) void mlp12_kernel(const float* __restrict__ x,
                                                    const int* __restrict__ idx,
                                                    const float* __restrict__ w1,
                                                    const float* __restrict__ w2,
                                                    unsigned short* __restrict__ h2HL,
                                                    unsigned short* __restrict__ catH,
                                                    unsigned short* __restrict__ catL) {
    __shared__ float w1s[64 * 6];
    __shared__ float w2s[64 * 68];
    __shared__ float fbuf[80][6];
    __shared__ float h1s[80 * 68];
    __shared__ float h2s[80 * 68];
    const int t = threadIdx.x;
    const int pbase = blockIdx.x * 16;

    for (int i = t; i < 384; i += 256) w1s[i] = w1[i];
    for (int i = t; i < 4096; i += 256) {
        int c = i >> 6, q = i & 63;
        w2s[c * 68 + q] = w2[i];
    }
    if (t < 80) {
        const int pt = pbase + t / 5;
        const int b = pt >> 13;
        const int n = pt & 8191;
        const int k = t % 5;
        const int j = idx[(size_t)pt * KNN + k];
        const float* xb = x + (size_t)b * 3 * NPTS;
        fbuf[t][0] = xb[j];
        fbuf[t][1] = xb[NPTS + j];
        fbuf[t][2] = xb[2 * NPTS + j];
        fbuf[t][3] = xb[n];
        fbuf[t][4] = xb[NPTS + n];
        fbuf[t][5] = xb[2 * NPTS + n];
    }
    __syncthreads();

    for (int o = t; o < 5120; o += 256) {
        const int r = o >> 6, c = o & 63;
        float acc = 0.f;
        #pragma unroll
        for (int q = 0; q < 6; ++q) acc = fmaf(w1s[c * 6 + q], fbuf[r][q], acc);
        h1s[r * 68 + c] = fmaxf(acc, 0.f);
    }
    __syncthreads();

    for (int o = t; o < 1024; o += 256) {
        const int p = o >> 6, c = o & 63;
        float m = h1s[(p * 5) * 68 + c];
        #pragma unroll
        for (int k = 1; k < 5; ++k) m = fmaxf(m, h1s[(p * 5 + k) * 68 + c]);
        const unsigned short hi = f2bf(m);
        const size_t co = (size_t)(pbase + p) * 512 + c;
        catH[co] = hi;
        catL[co] = f2bf(m - bf2f(hi));
    }

    for (int tile = t; tile < 320; tile += 256) {
        const int r0 = (tile % 20) * 4;
        const int c0 = (tile / 20) * 4;
        float acc[4][4] = {};
        for (int q = 0; q < 64; q += 4) {
            float4 a[4], w[4];
            #pragma unroll
            for (int i = 0; i < 4; ++i) a[i] = *(const float4*)&h1s[(r0 + i) * 68 + q];
            #pragma unroll
            for (int j = 0; j < 4; ++j) w[j] = *(const float4*)&w2s[(c0 + j) * 68 + q];
            #pragma unroll
            for (int i = 0; i < 4; ++i)
                #pragma unroll
                for (int j = 0; j < 4; ++j) {
                    acc[i][j] = fmaf(a[i].x, w[j].x, acc[i][j]);
                    acc[i][j] = fmaf(a[i].y, w[j].y, acc[i][j]);
                    acc[i][j] = fmaf(a[i].z, w[j].z, acc[i][j]);
                    acc[i][j] = fmaf(a[i].w, w[j].w, acc[i][j]);
                }
        }
        #pragma unroll
        for (int i = 0; i < 4; ++i)
            #pragma unroll
            for (int j = 0; j < 4; ++j)
                h2s[(r0 + i) * 68 + c0 + j] = fmaxf(acc[i][j], 0.f);
    }
    __syncthreads();

    for (int o = t; o < 1024; o += 256) {
        const int p = o >> 6, c = o & 63;
        float m = h2s[(p * 5) * 68 + c];
        #pragma unroll
        for (int k = 1; k < 5; ++k) m = fmaxf(m, h2s[(p * 5 + k) * 68 + c]);
        const unsigned short hi = f2bf(m);
        const size_t co = (size_t)(pbase + p) * 512 + 64 + c;
        catH[co] = hi;
        catL[co] = f2bf(m - bf2f(hi));
    }
    for (int o = t; o < 5120; o += 256) {
        const int r = o >> 6, c = o & 63;
        const float v = h2s[r * 68 + c];
        const unsigned short hi = f2bf(v);
        const size_t rowb = (size_t)(pbase * 5 + r) * 128;
        h2HL[rowb + c]      = hi;
        h2HL[rowb + 64 + c] = f2bf(v - bf2f(hi));
    }
}

// ---------------------------------------------------------------------------
// Kernel B2: L3 (64->128) via split-bf16 MFMA + x3max.
// ---------------------------------------------------------------------------
__global__ __launch_bounds__(256) void mlp3_kernel(
        const unsigned short* __restrict__ h2HL,
        const unsigned short* __restrict__ w3H, const unsigned short* __restrict__ w3L,
        unsigned short* __restrict__ h3H, unsigned short* __restrict__ h3L,
        unsigned short* __restrict__ catH, unsigned short* __restrict__ catL) {
    __shared__ __align__(16) char smem[59904];
    unsigned short* aH = (unsigned short*)smem;            // [80][72]
    unsigned short* aL = aH + 80 * 72;                     // @11520B
    unsigned short* bH = (unsigned short*)(smem + 23040);  // [128][72]
    unsigned short* bL = (unsigned short*)(smem + 41472);

    const int t = threadIdx.x;
    const int R0 = blockIdx.x * 80;
    const int P0 = blockIdx.x * 16;

    for (int c = t; c < 1280; c += 256) {                  // A: h2 hi|lo rows
        const int row = c >> 4, seg = c & 15;
        const uint4 v = *(const uint4*)(h2HL + (size_t)(R0 + row) * 128 + seg * 8);
        *(uint4*)((seg < 8 ? aH : aL) + row * 72 + (seg & 7) * 8) = v;
    }
    for (int c = t; c < 1024; c += 256) {                  // B hi
        const int row = c >> 3, seg = c & 7;
        *(uint4*)(bH + row * 72 + seg * 8) =
            *(const uint4*)(w3H + row * 64 + seg * 8);
    }
    for (int c = t; c < 1024; c += 256) {                  // B lo
        const int row = c >> 3, seg = c & 7;
        *(uint4*)(bL + row * 72 + seg * 8) =
            *(const uint4*)(w3L + row * 64 + seg * 8);
    }
    __syncthreads();

    const int w = t >> 6, lane = t & 63;
    const int q = lane >> 4, l16 = lane & 15;
    const int n0 = w * 32;

    f32x4 acc[5][2];
    #pragma unroll
    for (int mt = 0; mt < 5; ++mt)
        #pragma unroll
        for (int nt = 0; nt < 2; ++nt)
            acc[mt][nt] = (f32x4){0.f, 0.f, 0.f, 0.f};

    #pragma unroll
    for (int kt = 0; kt < 2; ++kt) {
        const int k0 = kt * 32 + q * 8;
        bf16x8 bh[2], bl[2];
        #pragma unroll
        for (int nt = 0; nt < 2; ++nt) {
            bh[nt] = *(const bf16x8*)(bH + (n0 + nt * 16 + l16) * 72 + k0);
            bl[nt] = *(const bf16x8*)(bL + (n0 + nt * 16 + l16) * 72 + k0);
        }
        #pragma unroll
        for (int mt = 0; mt < 5; ++mt) {
            const bf16x8 ah = *(const bf16x8*)(aH + (mt * 16 + l16) * 72 + k0);
            const bf16x8 al = *(const bf16x8*)(aL + (mt * 16 + l16) * 72 + k0);
            #pragma unroll
            for (int nt = 0; nt < 2; ++nt) {
                acc[mt][nt] = MFMA16(ah, bh[nt], acc[mt][nt]);
                acc[mt][nt] = MFMA16(ah, bl[nt], acc[mt][nt]);
                acc[mt][nt] = MFMA16(al, bh[nt], acc[mt][nt]);
            }
        }
    }

    __syncthreads();                       // A/B staging dead; alias Dbuf
    float* Dbuf = (float*)smem;            // [80][132] fp32
    #pragma unroll
    for (int mt = 0; mt < 5; ++mt)
        #pragma unroll
        for (int nt = 0; nt < 2; ++nt)
            #pragma unroll
            for (int r = 0; r < 4; ++r)
                Dbuf[(mt * 16 + q * 4 + r) * 132 + n0 + nt * 16 + l16] =
                    fmaxf(acc[mt][nt][r], 0.f);
    __syncthreads();

    {
        const int col = t & 127;
        const int p0 = (t >> 7) * 8;
        #pragma unroll
        for (int p = 0; p < 8; ++p) {
            const int pp = p0 + p;
            float mx = 0.f;
            #pragma unroll
            for (int k = 0; k < 5; ++k) {
                const int row = pp * 5 + k;
                const float v = Dbuf[row * 132 + col];
                const unsigned short hi = f2bf(v);
                const unsigned short lo = f2bf(v - bf2f(hi));
                const size_t off = (size_t)(R0 + row) * 128 + col;
                h3H[off] = hi;
                h3L[off] = lo;
                mx = fmaxf(mx, bf2f(hi) + bf2f(lo));
            }
            const unsigned short mh = f2bf(mx);
            const size_t co = (size_t)(P0 + pp) * 512 + 128 + col;
            catH[co] = mh;
            catL[co] = f2bf(mx - bf2f(mh));
        }
    }
}

// ---------------------------------------------------------------------------
// Kernel C: L4 (128->256) via split-bf16 MFMA + x4max.
// ---------------------------------------------------------------------------
__global__ __launch_bounds__(256) void mlp4_kernel(
        const unsigned short* __restrict__ h3H, const unsigned short* __restrict__ h3L,
        const unsigned short* __restrict__ w4H, const unsigned short* __restrict__ w4L,
        unsigned short* __restrict__ catH, unsigned short* __restrict__ catL) {
    __shared__ __align__(16) char smem[64000];
    unsigned short* aH = (unsigned short*)smem;            // [80][136]
    unsigned short* aL = aH + 80 * 136;                    // @21760B
    unsigned short* bH = (unsigned short*)(smem + 43520);  // [128][40] per k-step
    unsigned short* bL = (unsigned short*)(smem + 53760);

    const int t = threadIdx.x;
    const int R0 = blockIdx.x * 80;
    const int P0 = blockIdx.x * 16;
    const int ny = blockIdx.y;                             // cout half

    for (int c = t; c < 1280; c += 256) {                  // A hi
        const int row = c >> 4, seg = c & 15;
        *(uint4*)(aH + row * 136 + seg * 8) =
            *(const uint4*)(h3H + (size_t)(R0 + row) * 128 + seg * 8);
    }
    for (int c = t; c < 1280; c += 256) {                  // A lo
        const int row = c >> 4, seg = c & 15;
        *(uint4*)(aL + row * 136 + seg * 8) =
            *(const uint4*)(h3L + (size_t)(R0 + row) * 128 + seg * 8);
    }

    const int w = t >> 6, lane = t & 63;
    const int q = lane >> 4, l16 = lane & 15;
    const int n0 = w * 32;

    f32x4 acc[5][2];
    #pragma unroll
    for (int mt = 0; mt < 5; ++mt)
        #pragma unroll
        for (int nt = 0; nt < 2; ++nt)
            acc[mt][nt] = (f32x4){0.f, 0.f, 0.f, 0.f};

    for (int ks = 0; ks < 4; ++ks) {
        __syncthreads();
        #pragma unroll
        for (int i = 0; i < 2; ++i) {                      // B hi: 512 chunks
            const int c = t + i * 256;
            const int row = c >> 2, seg = c & 3;
            *(uint4*)(bH + row * 40 + seg * 8) =
                *(const uint4*)(w4H + (size_t)(ny * 128 + row) * 128 + ks * 32 + seg * 8);
        }
        #pragma unroll
        for (int i = 0; i < 2; ++i) {                      // B lo
            const int c = t + i * 256;
            const int row = c >> 2, seg = c & 3;
            *(uint4*)(bL + row * 40 + seg * 8) =
                *(const uint4*)(w4L + (size_t)(ny * 128 + row) * 128 + ks * 32 + seg * 8);
        }
        __syncthreads();

        const int k0 = ks * 32 + q * 8;
        const int kb = q * 8;
        bf16x8 bh[2], bl[2];
        #pragma unroll
        for (int nt = 0; nt < 2; ++nt) {
            bh[nt] = *(const bf16x8*)(bH + (n0 + nt * 16 + l16) * 40 + kb);
            bl[nt] = *(const bf16x8*)(bL + (n0 + nt * 16 + l16) * 40 + kb);
        }
        #pragma unroll
        for (int mt = 0; mt < 5; ++mt) {
            const bf16x8 ah = *(const bf16x8*)(aH + (mt * 16 + l16) * 136 + k0);
            const bf16x8 al = *(const bf16x8*)(aL + (mt * 16 + l16) * 136 + k0);
            #pragma unroll
            for (int nt = 0; nt < 2; ++nt) {
                acc[mt][nt] = MFMA16(ah, bh[nt], acc[mt][nt]);
                acc[mt][nt] = MFMA16(ah, bl[nt], acc[mt][nt]);
                acc[mt][nt] = MFMA16(al, bh[nt], acc[mt][nt]);
            }
        }
    }

    __syncthreads();
    float* Dbuf = (float*)smem;            // [80][132] fp32
    #pragma unroll
    for (int mt = 0; mt < 5; ++mt)
        #pragma unroll
        for (int nt = 0; nt < 2; ++nt)
            #pragma unroll
            for (int r = 0; r < 4; ++r)
                Dbuf[(mt * 16 + q * 4 + r) * 132 + n0 + nt * 16 + l16] =
                    fmaxf(acc[mt][nt][r], 0.f);
    __syncthreads();

    {
        const int col = t & 127;
        const int p0 = (t >> 7) * 8;
        const int cout = 256 + ny * 128 + col;
        #pragma unroll
        for (int p = 0; p < 8; ++p) {
            const int pp = p0 + p;
            float mx = 0.f;
            #pragma unroll
            for (int k = 0; k < 5; ++k)
                mx = fmaxf(mx, Dbuf[(pp * 5 + k) * 132 + col]);
            const unsigned short mh = f2bf(mx);
            const size_t co = (size_t)(P0 + pp) * 512 + cout;
            catH[co] = mh;
            catL[co] = f2bf(mx - bf2f(mh));
        }
    }
}

// ---------------------------------------------------------------------------
// Kernel D: final GEMM out = relu(cat(32768x512) * W5^T) via split-bf16 MFMA.
// ---------------------------------------------------------------------------
__global__ __launch_bounds__(256) void gemm512_kernel(
        const unsigned short* __restrict__ catH, const unsigned short* __restrict__ catL,
        const unsigned short* __restrict__ w5H, const unsigned short* __restrict__ w5L,
        float* __restrict__ out) {
    __shared__ __align__(16) char smem[40960];
    unsigned short* aH = (unsigned short*)smem;            // [128][40]
    unsigned short* aL = aH + 128 * 40;                    // @10240B
    unsigned short* bH = (unsigned short*)(smem + 20480);
    unsigned short* bL = (unsigned short*)(smem + 30720);

    const int t = threadIdx.x;
    const int m0 = blockIdx.x * 128;
    const int n0blk = blockIdx.y * 128;

    const int w = t >> 6, lane = t & 63;
    const int q = lane >> 4, l16 = lane & 15;
    const int m_off = (w >> 1) * 64;
    const int n_off = (w & 1) * 64;

    f32x4 acc[4][4];
    #pragma unroll
    for (int mt = 0; mt < 4; ++mt)
        #pragma unroll
        for (int nt = 0; nt < 4; ++nt)
            acc[mt][nt] = (f32x4){0.f, 0.f, 0.f, 0.f};

    for (int kc = 0; kc < 512; kc += 32) {
        __syncthreads();
        #pragma unroll
        for (int i = 0; i < 2; ++i) {
            const int c = t + i * 256;
            const int row = c >> 2, seg = c & 3;
            *(uint4*)(aH + row * 40 + seg * 8) =
                *(const uint4*)(catH + (size_t)(m0 + row) * 512 + kc + seg * 8);
        }
        #pragma unroll
        for (int i = 0; i < 2; ++i) {
            const int c = t + i * 256;
            const int row = c >> 2, seg = c & 3;
            *(uint4*)(aL + row * 40 + seg * 8) =
                *(const uint4*)(catL + (size_t)(m0 + row) * 512 + kc + seg * 8);
        }
        #pragma unroll
        for (int i = 0; i < 2; ++i) {
            const int c = t + i * 256;
            const int row = c >> 2, seg = c & 3;
            *(uint4*)(bH + row * 40 + seg * 8) =
                *(const uint4*)(w5H + (size_t)(n0blk + row) * 512 + kc + seg * 8);
        }
        #pragma unroll
        for (int i = 0; i < 2; ++i) {
            const int c = t + i * 256;
            const int row = c >> 2, seg = c & 3;
            *(uint4*)(bL + row * 40 + seg * 8) =
                *(const uint4*)(w5L + (size_t)(n0blk + row) * 512 + kc + seg * 8);
        }
        __syncthreads();

        const int k0 = q * 8;
        bf16x8 bh[4], bl[4];
        #pragma unroll
        for (int nt = 0; nt < 4; ++nt) {
            bh[nt] = *(const bf16x8*)(bH + (n_off + nt * 16 + l16) * 40 + k0);
            bl[nt] = *(const bf16x8*)(bL + (n_off + nt * 16 + l16) * 40 + k0);
        }
        #pragma unroll
        for (int mt = 0; mt < 4; ++mt) {
            const bf16x8 ah = *(const bf16x8*)(aH + (m_off + mt * 16 + l16) * 40 + k0);
            const bf16x8 al = *(const bf16x8*)(aL + (m_off + mt * 16 + l16) * 40 + k0);
            #pragma unroll
            for (int nt = 0; nt < 4; ++nt) {
                acc[mt][nt] = MFMA16(ah, bh[nt], acc[mt][nt]);
                acc[mt][nt] = MFMA16(ah, bl[nt], acc[mt][nt]);
                acc[mt][nt] = MFMA16(al, bh[nt], acc[mt][nt]);
            }
        }
    }

    // band-wise epilogue: 8 bands of 16 rows; LDS transpose for coalesced out
    float* bandbuf = (float*)smem;         // [16][132] fp32
    for (int b8 = 0; b8 < 8; ++b8) {
        __syncthreads();
        if ((w >> 1) == (b8 >> 2)) {
            const int mt = b8 & 3;
            #pragma unroll
            for (int nt = 0; nt < 4; ++nt)
                #pragma unroll
                for (int r = 0; r < 4; ++r)
                    bandbuf[(q * 4 + r) * 132 + n_off + nt * 16 + l16] =
                        fmaxf(acc[mt][nt][r], 0.f);
        }
        __syncthreads();
        const int col = t >> 1;
        const int ph = (t & 1) * 8;
        const int P = m0 + b8 * 16 + ph;
        const int bb = P >> 13, nn = P & 8191;
        const int cout = n0blk + col;
        float tmp[8];
        #pragma unroll
        for (int j = 0; j < 8; ++j) tmp[j] = bandbuf[(ph + j) * 132 + col];
        float* op = &out[((size_t)bb * 512 + cout) * NPTS + nn];
        *(float4*)op       = make_float4(tmp[0], tmp[1], tmp[2], tmp[3]);
        *(float4*)(op + 4) = make_float4(tmp[4], tmp[5], tmp[6], tmp[7]);
    }
}

extern "C" void kernel_launch(void* const* d_in, const int* in_sizes, int n_in,
                              void* d_out, int out_size, void* d_ws, size_t ws_size,
                              hipStream_t stream) {
    (void)in_sizes; (void)n_in; (void)out_size; (void)ws_size;
    const float* x  = (const float*)d_in[0];
    const float* w1 = (const float*)d_in[1];
    const float* w2 = (const float*)d_in[2];
    const float* w3 = (const float*)d_in[3];
    const float* w4 = (const float*)d_in[4];
    const float* w5 = (const float*)d_in[5];
    float* out = (float*)d_out;

    // workspace layout (111.2 MB total, < proven 145 MB)
    char* ws = (char*)d_ws;
    unsigned short* w3H = (unsigned short*)(ws + 0);          //  16384 B
    unsigned short* w3L = (unsigned short*)(ws + 16384);
    unsigned short* w4H = (unsigned short*)(ws + 32768);      //  65536 B
    unsigned short* w4L = (unsigned short*)(ws + 98304);
    unsigned short* w5H = (unsigned short*)(ws + 163840);     // 524288 B
    unsigned short* w5L = (unsigned short*)(ws + 688128);
    int*            idx = (int*)(ws + 1212416);               // 655360 B
    unsigned short* catH = (unsigned short*)(ws + 2097152);   // 33.55 MB
    unsigned short* catL = (unsigned short*)(ws + 35651584);  // 33.55 MB
    unsigned short* h3H  = (unsigned short*)(ws + 69206016);  // 41.94 MB
    // d_out doubles as scratch: h2 (hi|lo interleaved) then h3L in-place
    unsigned short* h2HL = (unsigned short*)d_out;
    unsigned short* h3L  = (unsigned short*)d_out;

    wsplit_kernel<<<dim3(1184), dim3(256), 0, stream>>>(w3, w4, w5,
                                                        w3H, w3L, w4H, w4L, w5H, w5L);
    knn_kernel<<<dim3(BATCH * NPTS / 64), dim3(512), 0, stream>>>(x, idx);
    mlp12_kernel<<<dim3(BATCH * NPTS / 16), dim3(256), 0, stream>>>(x, idx, w1, w2,
                                                                    h2HL, catH, catL);
    mlp3_kernel<<<dim3(BATCH * NPTS * KNN / 80), dim3(256), 0, stream>>>(
        h2HL, w3H, w3L, h3H, h3L, catH, catL);
    mlp4_kernel<<<dim3(BATCH * NPTS * KNN / 80, 2), dim3(256), 0, stream>>>(
        h3H, h3L, w4H, w4L, catH, catL);
    gemm512_kernel<<<dim3(BATCH * NPTS / 128, 4), dim3(256), 0, stream>>>(
        catH, catL, w5H, w5L, out);
}